// Round 7
// baseline (340.866 us; speedup 1.0000x reference)
//
#include <hip/hip_runtime.h>
#include <stdint.h>

typedef unsigned short u16;
typedef __bf16 bf16x8 __attribute__((ext_vector_type(8)));
typedef float f32x4 __attribute__((ext_vector_type(4)));

#define AS1(p) ((const __attribute__((address_space(1))) void*)(p))
#define AS3(p) ((__attribute__((address_space(3))) void*)(p))

__device__ __forceinline__ float b2f(u16 v){
    union { unsigned u; float f; } x; x.u = ((unsigned)v) << 16; return x.f;
}
__device__ __forceinline__ u16 f2b(float f){
    union { float f; unsigned u; } x; x.f = f;
    unsigned r = x.u + 0x7FFFu + ((x.u >> 16) & 1u);
    return (u16)(r >> 16);
}

// ---------------- dtype probe: one block per input tensor (unchanged, proven) ----------------
__global__ __launch_bounds__(256) void probe_kernel(
    const u16* p0,const u16* p1,const u16* p2,const u16* p3,const u16* p4,
    const u16* p5,const u16* p6,const u16* p7,const u16* p8,const u16* p9,
    const u16* p10,const u16* p11,const u16* p12,
    int n0,int n1,int n2,int n3,int n4,int n5,int n6,int n7,int n8,int n9,
    int n10,int n11,int n12, int* flags)
{
    const u16* p; int n;
    switch (blockIdx.x) {
        case 0: p=p0; n=n0; break;   case 1: p=p1; n=n1; break;
        case 2: p=p2; n=n2; break;   case 3: p=p3; n=n3; break;
        case 4: p=p4; n=n4; break;   case 5: p=p5; n=n5; break;
        case 6: p=p6; n=n6; break;   case 7: p=p7; n=n7; break;
        case 8: p=p8; n=n8; break;   case 9: p=p9; n=n9; break;
        case 10: p=p10; n=n10; break; case 11: p=p11; n=n11; break;
        default: p=p12; n=n12; break;
    }
    int pairs = n >> 1; if (pairs > 2048) pairs = 2048;
    int strong = 0, znz = 0, tot = 0;
    for (int k = threadIdx.x; k < pairs; k += 256) {
        u16 lo = p[2*k], hi = p[2*k+1];
        int eh = (hi >> 7) & 0xFF;
        int el = (lo >> 7) & 0xFF;
        if (eh >= 0xF0 || (eh >= 1 && eh <= 0x40)) strong = 1;
        if (el >= 0xF0 || (el >= 1 && el <= 0x40)) strong = 1;
        if (lo == 0 && hi != 0) znz++;
        tot++;
    }
    __shared__ int ss, sz, st;
    if (threadIdx.x == 0) { ss = 0; sz = 0; st = 0; }
    __syncthreads();
    if (strong) atomicOr(&ss, 1);
    if (znz) atomicAdd(&sz, znz);
    atomicAdd(&st, tot);
    __syncthreads();
    if (threadIdx.x == 0) {
        flags[blockIdx.x] = (ss || (2 * sz > st)) ? 1 : 0;
        if (blockIdx.x == 0) flags[15] = 0;
    }
}

// ---------------- convert weight/vector tensors to bf16 (Tf -> f32) in ws (unchanged) -----------
__global__ __launch_bounds__(256) void convert_kernel(
    const void* sWc, const void* sW2, const void* sW1,
    const void* sTa, const void* sBc, const void* sG1, const void* sB1l,
    const void* sTf, const void* sB1, const void* sB2, const void* sG2, const void* sB2l,
    u16* wbase, const int* flags)
{
    int b = blockIdx.x;
    const void* src; u16* dst; int n, fi, lb, tof32 = 0;
    if (b < 128)      { src=sWc; dst=wbase;          n=262144;  fi=2;  lb=b; }
    else if (b < 640) { src=sW2; dst=wbase+262144;   n=1048576; fi=9;  lb=b-128; }
    else if (b >= 643 && b < 651) { src=sW1; dst=wbase+1312256; n=16384; fi=7; lb=b-643; }
    else {
        lb = 0;
        switch (b) {
            case 640: src=sTa;  dst=wbase+1310720; n=512;  fi=1;  break;
            case 641: src=sBc;  dst=wbase+1311232; n=512;  fi=3;  break;
            case 642: src=sB2;  dst=wbase+1311744; n=512;  fi=10; break;
            case 651: src=sB1;  dst=wbase+1328640; n=2048; fi=8;  break;
            case 652: src=sG1;  dst=wbase+1330688; n=512;  fi=4;  break;
            case 653: src=sB1l; dst=wbase+1331200; n=512;  fi=5;  break;
            case 654: src=sG2;  dst=wbase+1331712; n=512;  fi=11; break;
            case 655: src=sB2l; dst=wbase+1332224; n=512;  fi=12; break;
            default:  src=sTf;  dst=wbase+1332736; n=8;    fi=6;  tof32=1; break;
        }
    }
    int i = lb * 256 + threadIdx.x;
    if (i * 8 >= n) return;
    if (tof32) {
        float* fd = (float*)dst;
        if (flags[fi]) {
            const float4* s = (const float4*)src;
            ((float4*)fd)[i*2] = s[i*2]; ((float4*)fd)[i*2+1] = s[i*2+1];
        } else {
            union { uint4 v; u16 h[8]; } sb;
            sb.v = ((const uint4*)src)[i];
            #pragma unroll
            for (int j = 0; j < 8; j++) fd[i*8+j] = b2f(sb.h[j]);
        }
        return;
    }
    if (flags[fi]) {
        const float4* s = (const float4*)src;
        float4 a = s[i*2], c = s[i*2+1];
        union { uint4 v; u16 h[8]; } o;
        o.h[0]=f2b(a.x); o.h[1]=f2b(a.y); o.h[2]=f2b(a.z); o.h[3]=f2b(a.w);
        o.h[4]=f2b(c.x); o.h[5]=f2b(c.y); o.h[6]=f2b(c.z); o.h[7]=f2b(c.w);
        ((uint4*)dst)[i] = o.v;
    } else {
        ((uint4*)dst)[i] = ((const uint4*)src)[i];
    }
}

// ---------------- qgen: q[m,k] = bf16(cos(x[m,k] + theta[k])) — pure streaming ----------------
__global__ __launch_bounds__(256) void qgen_kernel(
    const void* __restrict__ x, const u16* __restrict__ theta,
    u16* __restrict__ q, const int* flags)
{
    const int idx = blockIdx.x * 256 + threadIdx.x;   // octet index, 2,097,152 total
    const int col0 = (idx * 8) & 511;
    union { uint4 v; u16 h[8]; } tb;
    tb.v = *(const uint4*)(theta + col0);
    float xv[8];
    if (flags[0]) {
        const float4* p = (const float4*)x + idx * 2;
        float4 a = p[0], b = p[1];
        xv[0]=a.x; xv[1]=a.y; xv[2]=a.z; xv[3]=a.w;
        xv[4]=b.x; xv[5]=b.y; xv[6]=b.z; xv[7]=b.w;
    } else {
        union { uint4 v; u16 h[8]; } xb;
        xb.v = ((const uint4*)x)[idx];
        #pragma unroll
        for (int e = 0; e < 8; e++) xv[e] = b2f(xb.h[e]);
    }
    union { uint4 v; u16 h[8]; } o;
    #pragma unroll
    for (int e = 0; e < 8; e++) o.h[e] = f2b(__cosf(xv[e] + b2f(tb.h[e])));
    ((uint4*)q)[idx] = o.v;
}

// ======== gemm1: y1[m,n] = sum_k q[m,k]*Wc[n,k] + bc[n] + x[m,n] ========
// Pure bf16 GEMM, m97-family (unchanged — below gemm2 in the profile).
__global__ __launch_bounds__(256, 3) void gemm1_fused(
    const u16* __restrict__ q, const void* __restrict__ x,
    const u16* __restrict__ Wt, const u16* __restrict__ bias,
    u16* __restrict__ dst, int mtiles, const int* flags)
{
    __shared__ __align__(16) u16 As[2][128 * 64];
    __shared__ __align__(16) u16 Bs[2][128 * 64];
    const int K = 512, N = 512;
    const int tid  = threadIdx.x;
    const int lane = tid & 63;
    const int w    = tid >> 6;

    const int blk = blockIdx.x;
    const int xcd = blk & 7;
    const int j   = blk >> 3;
    const int per = mtiles >> 3;
    const int mt  = xcd * per + (j >> 2);
    const int nt  = j & 3;
    const int m0 = mt * 128;
    const int n0 = nt * 128;

    const int srow = lane >> 3;
    const int scol = ((lane & 7) ^ srow) * 8;
    const int wm = (w >> 1) * 64;
    const int wn = (w & 1) * 64;
    const int fr   = lane & 15;
    const int quad = lane >> 4;
    const int fx   = fr & 7;
    const int isf32 = flags[0];

    f32x4 acc[4][4];
    #pragma unroll
    for (int i = 0; i < 4; i++)
        #pragma unroll
        for (int jj = 0; jj < 4; jj++)
            acc[i][jj] = f32x4{0.f, 0.f, 0.f, 0.f};

    const u16* Abase = q  + (size_t)m0 * K + scol;
    const u16* Bbase = Wt + (size_t)n0 * K + scol;

    // prologue: stage buf 0 (A + B)
    #pragma unroll
    for (int i = 0; i < 4; i++) {
        int c = w * 4 + i;
        int row = c * 8 + srow;
        __builtin_amdgcn_global_load_lds(AS1(Abase + (size_t)row * K),
                                         AS3(&As[0][c * 512]), 16, 0, 0);
        __builtin_amdgcn_global_load_lds(AS1(Bbase + (size_t)row * K),
                                         AS3(&Bs[0][c * 512]), 16, 0, 0);
    }

    int cur = 0;
    for (int kt = 0; kt < K; kt += 64) {
        __syncthreads();               // buf[cur] staged (vmcnt drained at barrier)
        if (kt + 64 < K) {             // issue next-tile staging; flies under MFMA phase
            int nxt = cur ^ 1;
            #pragma unroll
            for (int i = 0; i < 4; i++) {
                int c = w * 4 + i;
                int row = c * 8 + srow;
                __builtin_amdgcn_global_load_lds(
                    AS1(Abase + (size_t)row * K + kt + 64),
                    AS3(&As[nxt][c * 512]), 16, 0, 0);
                __builtin_amdgcn_global_load_lds(
                    AS1(Bbase + (size_t)row * K + kt + 64),
                    AS3(&Bs[nxt][c * 512]), 16, 0, 0);
            }
        }
        #pragma unroll
        for (int kk = 0; kk < 2; kk++) {
            bf16x8 af[4], bfr[4];
            #pragma unroll
            for (int mi = 0; mi < 4; mi++)
                af[mi] = *(const bf16x8*)(&As[cur][(wm + mi * 16 + fr) * 64 +
                                          (((kk * 4 + quad) ^ fx) * 8)]);
            #pragma unroll
            for (int ni = 0; ni < 4; ni++)
                bfr[ni] = *(const bf16x8*)(&Bs[cur][(wn + ni * 16 + fr) * 64 +
                                           (((kk * 4 + quad) ^ fx) * 8)]);
            #pragma unroll
            for (int mi = 0; mi < 4; mi++)
                #pragma unroll
                for (int ni = 0; ni < 4; ni++)
                    acc[mi][ni] = __builtin_amdgcn_mfma_f32_16x16x32_bf16(
                        af[mi], bfr[ni], acc[mi][ni], 0, 0, 0);
        }
        cur ^= 1;
    }

    #pragma unroll
    for (int mi = 0; mi < 4; mi++) {
        #pragma unroll
        for (int ni = 0; ni < 4; ni++) {
            int n = n0 + wn + ni * 16 + fr;
            float bn = b2f(bias[n]);
            #pragma unroll
            for (int r = 0; r < 4; r++) {
                int m = m0 + wm + mi * 16 + quad * 4 + r;
                float rv = isf32 ? ((const float*)x)[(size_t)m * N + n]
                                 : b2f(((const u16*)x)[(size_t)m * N + n]);
                dst[(size_t)m * N + n] = f2b(acc[mi][ni][r] + bn + rv);
            }
        }
    }
}

// ======== gemm2 + fused LN2: out = LN(h@W2 + b2 + x1) ========
// R5 geometry (95us measured, best of family): BM=128 x BN=512 x BK=64, 8 waves as
// 2m x 4n, wave = 64m x 128n, acc[4][8]. Register h-gen (proven identity), Bs dbuf
// 128KB, 1 barrier/K-step, grid 256 = 1 block/CU.
// NEW: block holds COMPLETE z rows (BN=512=N) -> LayerNorm fused into the epilogue:
// fold bias+residual into acc (=z), row-sums over nq, shfl_xor reduce over 16-lane
// fr group, cross-wave (4 n-waves) partials through LDS (Bs reused, idle here),
// normalized store straight to d_out (dtype per flags). Kills the ln2 kernel:
// saves 33MB z write + 33MB z read + one dispatch.
__global__ __launch_bounds__(512, 2) void gemm2_fused(
    const u16* __restrict__ fq, const u16* __restrict__ W1, const u16* __restrict__ b1,
    const u16* __restrict__ Wt, const u16* __restrict__ bias,
    const u16* __restrict__ res, const u16* __restrict__ g2, const u16* __restrict__ b2l,
    void* __restrict__ out, const int* flags)
{
    __shared__ __align__(16) u16 Bs[2][512 * 64];
    const int K = 2048, N = 512;
    const int tid  = threadIdx.x;
    const int lane = tid & 63;
    const int w    = tid >> 6;

    const int m0 = blockIdx.x * 128;

    const int srow = lane >> 3;
    const int scol = ((lane & 7) ^ srow) * 8;
    const int wm = (w >> 2) * 64;          // 2 waves per 64-row m-range
    const int wn = (w & 3) * 128;          // 4 n-positions of 128
    const int fr   = lane & 15;
    const int quad = lane >> 4;
    const int fx   = fr & 7;
    const int isf32 = flags[0];

    // fq B-frags for h-gen: wave's own 4 m-subtiles (m = m0+wm+mi*16+fr), quad0 holds data.
    bf16x8 fqf[4];
    #pragma unroll
    for (int mi = 0; mi < 4; mi++) {
        union { uint4 v; bf16x8 b; } z; z.v = uint4{0,0,0,0};
        if (quad == 0) z.v = *(const uint4*)(fq + (size_t)(m0 + wm + mi * 16 + fr) * 8);
        fqf[mi] = z.b;
    }

    // interleaved W1-row index for h-gen MFMA g (quad0 lanes supply A rows):
    const int krow = ((fr >> 2) * 8) + (fr & 3);      // + kt + (g>>1)*32 + (g&1)*4

    // W1 frags + b1 frags for kt=0 (proven layout)
    union { uint4 v; bf16x8 b; } w1f[4];
    uint2 b1f[4];
    #pragma unroll
    for (int g = 0; g < 4; g++) {
        w1f[g].v = uint4{0,0,0,0};
        if (quad == 0)
            w1f[g].v = *(const uint4*)(W1 + (size_t)((g >> 1) * 32 + (g & 1) * 4 + krow) * 8);
        b1f[g] = *(const uint2*)(b1 + (g >> 1) * 32 + (g & 1) * 4 + quad * 8);
    }

    f32x4 acc[4][8];
    #pragma unroll
    for (int i = 0; i < 4; i++)
        #pragma unroll
        for (int jj = 0; jj < 8; jj++)
            acc[i][jj] = f32x4{0.f, 0.f, 0.f, 0.f};

    // B staging: rows are n (0..511), full N. 8 row-groups of 8 per wave-issue set.
    const u16* Bbase = Wt + scol;
    #pragma unroll
    for (int i = 0; i < 8; i++) {
        int c = w * 8 + i;
        int row = c * 8 + srow;
        __builtin_amdgcn_global_load_lds(AS1(Bbase + (size_t)row * K),
                                         AS3(&Bs[0][c * 512]), 16, 0, 0);
    }

    int cur = 0;
    for (int kt = 0; kt < K; kt += 64) {
        __syncthreads();               // Bs[cur] staged, w1f/b1f for this kt ready
        if (kt + 64 < K) {             // issue next Bs staging; flies under compute
            int nxt = cur ^ 1;
            #pragma unroll
            for (int i = 0; i < 8; i++) {
                int c = w * 8 + i;
                int row = c * 8 + srow;
                __builtin_amdgcn_global_load_lds(
                    AS1(Bbase + (size_t)row * K + kt + 64),
                    AS3(&Bs[nxt][c * 512]), 16, 0, 0);
            }
        }
        #pragma unroll
        for (int kk = 0; kk < 2; kk++) {
            // ---- h-gen: af for all 4 mi (register-direct, proven identity) ----
            const u16* pb0 = (const u16*)&b1f[kk * 2 + 0];
            const u16* pb1 = (const u16*)&b1f[kk * 2 + 1];
            f32x4 c0 = {b2f(pb0[0]), b2f(pb0[1]), b2f(pb0[2]), b2f(pb0[3])};
            f32x4 c1 = {b2f(pb1[0]), b2f(pb1[1]), b2f(pb1[2]), b2f(pb1[3])};
            bf16x8 af[4];
            #pragma unroll
            for (int mi = 0; mi < 4; mi++) {
                f32x4 hv0 = __builtin_amdgcn_mfma_f32_16x16x32_bf16(
                    w1f[kk * 2 + 0].b, fqf[mi], c0, 0, 0, 0);
                f32x4 hv1 = __builtin_amdgcn_mfma_f32_16x16x32_bf16(
                    w1f[kk * 2 + 1].b, fqf[mi], c1, 0, 0, 0);
                #pragma unroll
                for (int r = 0; r < 4; r++) {
                    af[mi][r]     = (__bf16)fmaxf(hv0[r], 0.f);
                    af[mi][4 + r] = (__bf16)fmaxf(hv1[r], 0.f);
                }
            }
            // ---- main MFMA over the wave's 128 n, bfr in PAIRS ----
            #pragma unroll
            for (int np = 0; np < 4; np++) {
                bf16x8 bfr[2];
                #pragma unroll
                for (int ni = 0; ni < 2; ni++)
                    bfr[ni] = *(const bf16x8*)(&Bs[cur][(wn + (np * 2 + ni) * 16 + fr) * 64 +
                                               (((kk * 4 + quad) ^ fx) * 8)]);
                #pragma unroll
                for (int mi = 0; mi < 4; mi++)
                    #pragma unroll
                    for (int ni = 0; ni < 2; ni++)
                        acc[mi][np * 2 + ni] = __builtin_amdgcn_mfma_f32_16x16x32_bf16(
                            af[mi], bfr[ni], acc[mi][np * 2 + ni], 0, 0, 0);
            }
        }
        // prefetch next kt's W1/b1 frags (tiny, L1/L2-resident)
        if (kt + 64 < K) {
            #pragma unroll
            for (int g = 0; g < 4; g++) {
                if (quad == 0)
                    w1f[g].v = *(const uint4*)(W1 +
                        (size_t)(kt + 64 + (g >> 1) * 32 + (g & 1) * 4 + krow) * 8);
                b1f[g] = *(const uint2*)(b1 + kt + 64 + (g >> 1) * 32 + (g & 1) * 4 + quad * 8);
            }
        }
        cur ^= 1;
    }

    // ================= fused LN2 epilogue =================
    __syncthreads();                    // all waves done with Bs -> reuse as reduce scratch

    // fold bias + residual into acc => acc holds z
    #pragma unroll
    for (int mi = 0; mi < 4; mi++) {
        #pragma unroll
        for (int nq = 0; nq < 8; nq++) {
            int n = wn + nq * 16 + fr;
            float bn = b2f(bias[n]);
            #pragma unroll
            for (int r = 0; r < 4; r++) {
                int m = m0 + wm + mi * 16 + quad * 4 + r;
                acc[mi][nq][r] += bn + b2f(res[(size_t)m * N + n]);
            }
        }
    }

    // per-row partial sums over this wave's 128 n (8 nq x 16 fr lanes)
    float s[4][4], sq[4][4];
    #pragma unroll
    for (int mi = 0; mi < 4; mi++)
        #pragma unroll
        for (int r = 0; r < 4; r++) {
            float a = 0.f, b = 0.f;
            #pragma unroll
            for (int nq = 0; nq < 8; nq++) {
                float v = acc[mi][nq][r];
                a += v; b += v * v;
            }
            s[mi][r] = a; sq[mi][r] = b;
        }
    #pragma unroll
    for (int o = 1; o < 16; o <<= 1) {
        #pragma unroll
        for (int mi = 0; mi < 4; mi++)
            #pragma unroll
            for (int r = 0; r < 4; r++) {
                s[mi][r]  += __shfl_xor(s[mi][r],  o);
                sq[mi][r] += __shfl_xor(sq[mi][r], o);
            }
    }
    // cross-wave reduce through LDS: [row 0..127][wnIdx 0..3] float2{s,sq}
    float2* red = (float2*)(&Bs[0][0]);
    if (fr == 0) {
        #pragma unroll
        for (int mi = 0; mi < 4; mi++)
            #pragma unroll
            for (int r = 0; r < 4; r++) {
                int row = wm + mi * 16 + quad * 4 + r;
                red[row * 4 + (w & 3)] = float2{s[mi][r], sq[mi][r]};
            }
    }
    __syncthreads();

    #pragma unroll
    for (int mi = 0; mi < 4; mi++) {
        float mu[4], rs[4];
        #pragma unroll
        for (int r = 0; r < 4; r++) {
            int row = wm + mi * 16 + quad * 4 + r;
            float S = 0.f, SS = 0.f;
            #pragma unroll
            for (int jj = 0; jj < 4; jj++) {
                float2 p = red[row * 4 + jj];
                S += p.x; SS += p.y;
            }
            float m_ = S * (1.f / 512.f);
            mu[r] = m_;
            rs[r] = rsqrtf(SS * (1.f / 512.f) - m_ * m_ + 1e-5f);
        }
        #pragma unroll
        for (int nq = 0; nq < 8; nq++) {
            int n = wn + nq * 16 + fr;
            float gv = b2f(g2[n]);
            float bv = b2f(b2l[n]);
            #pragma unroll
            for (int r = 0; r < 4; r++) {
                int m = m0 + wm + mi * 16 + quad * 4 + r;
                float val = (acc[mi][nq][r] - mu[r]) * rs[r] * gv + bv;
                if (isf32) ((float*)out)[(size_t)m * N + n] = val;
                else       ((u16*)out)[(size_t)m * N + n] = f2b(val);
            }
        }
    }
}

// ------- ln1: x1 = LN(y1)*g+b; fq = cos(x1[:,:8]+tf)  (h generation stays in gemm2) -------
__global__ __launch_bounds__(512) void ln1_kernel(
    const u16* __restrict__ y1, const u16* __restrict__ g, const u16* __restrict__ b,
    const float* __restrict__ tf, u16* __restrict__ x1, u16* __restrict__ fqout)
{
    __shared__ __align__(16) float xs8[64][8];
    const int t = threadIdx.x;
    const int wv = t >> 6, l = t & 63;
    const size_t rbase = (size_t)blockIdx.x * 64;

    union { uint4 v; u16 s[8]; } gb, bb;
    gb.v = *(const uint4*)(g + l * 8);
    bb.v = *(const uint4*)(b + l * 8);

    #pragma unroll
    for (int i = 0; i < 8; i++) {
        int lr = wv * 8 + i;
        union { uint4 v; u16 s[8]; } yb;
        yb.v = ((const uint4*)(y1 + (rbase + lr) * 512))[l];
        float xv[8], s = 0.f, ss = 0.f;
        #pragma unroll
        for (int jj = 0; jj < 8; jj++) {
            xv[jj] = b2f(yb.s[jj]); s += xv[jj]; ss += xv[jj] * xv[jj];
        }
        #pragma unroll
        for (int o = 32; o > 0; o >>= 1) { s += __shfl_down(s, o); ss += __shfl_down(ss, o); }
        s = __shfl(s, 0); ss = __shfl(ss, 0);
        float mu = s * (1.f / 512.f);
        float rs = rsqrtf(ss * (1.f / 512.f) - mu * mu + 1e-5f);
        union { uint4 v; u16 s[8]; } ob;
        float xn[8];
        #pragma unroll
        for (int jj = 0; jj < 8; jj++) {
            xn[jj] = (xv[jj] - mu) * rs * b2f(gb.s[jj]) + b2f(bb.s[jj]);
            ob.s[jj] = f2b(xn[jj]);
        }
        ((uint4*)(x1 + (rbase + lr) * 512))[l] = ob.v;
        if (l == 0) {
            #pragma unroll
            for (int jj = 0; jj < 8; jj++) xs8[lr][jj] = xn[jj];
        }
    }
    __syncthreads();
    {
        int r = t >> 3, jj = t & 7;
        fqout[(rbase + r) * 8 + jj] = f2b(__cosf(xs8[r][jj] + tf[jj]));
    }
}

extern "C" void kernel_launch(void* const* d_in, const int* in_sizes, int n_in,
                              void* d_out, int out_size, void* d_ws, size_t ws_size,
                              hipStream_t stream)
{
    u16* ws16 = (u16*)d_ws;
    // ws (u16 elems): W [0,1332752) | flags @1332752 | fq @1332800 (262144)
    //                 x1 @1594944 (16.7M) | y1 @18372160 (16.7M)
    // q (cos(x+theta), bf16) ALIASES the x1 region: q live [qgen, gemm1); x1 written by ln1 after.
    // z is never materialized: LN2 fused into gemm2's epilogue -> writes d_out directly.
    u16* W     = ws16;
    int* flags = (int*)(ws16 + 1332752);
    u16* fq  = ws16 + 1332800;
    u16* x1  = ws16 + 1594944;
    u16* q   = x1;
    u16* y1  = ws16 + 18372160;

    const u16*  wWc  = W;
    const u16*  wW2  = W + 262144;
    const u16*  wTa  = W + 1310720;
    const u16*  wBc  = W + 1311232;
    const u16*  wB2  = W + 1311744;
    const u16*  wW1  = W + 1312256;
    const u16*  wB1  = W + 1328640;
    const u16*  wG1  = W + 1330688;
    const u16*  wB1l = W + 1331200;
    const u16*  wG2  = W + 1331712;
    const u16*  wB2l = W + 1332224;
    const float* wTf = (const float*)(W + 1332736);

    probe_kernel<<<13, 256, 0, stream>>>(
        (const u16*)d_in[0], (const u16*)d_in[1], (const u16*)d_in[2],
        (const u16*)d_in[3], (const u16*)d_in[4], (const u16*)d_in[5],
        (const u16*)d_in[6], (const u16*)d_in[7], (const u16*)d_in[8],
        (const u16*)d_in[9], (const u16*)d_in[10], (const u16*)d_in[11],
        (const u16*)d_in[12],
        in_sizes[0], in_sizes[1], in_sizes[2], in_sizes[3], in_sizes[4],
        in_sizes[5], in_sizes[6], in_sizes[7], in_sizes[8], in_sizes[9],
        in_sizes[10], in_sizes[11], in_sizes[12], flags);

    convert_kernel<<<657, 256, 0, stream>>>(
        d_in[2], d_in[9], d_in[7], d_in[1], d_in[3], d_in[4], d_in[5],
        d_in[6], d_in[8], d_in[10], d_in[11], d_in[12], (u16*)W, flags);

    qgen_kernel<<<8192, 256, 0, stream>>>(d_in[0], wTa, q, flags);

    gemm1_fused<<<1024, 256, 0, stream>>>(
        q, d_in[0], wWc, wBc, y1, 256, flags);

    ln1_kernel<<<512, 512, 0, stream>>>(y1, wG1, wB1l, wTf, x1, fq);

    gemm2_fused<<<256, 512, 0, stream>>>(
        fq, wW1, wB1, wW2, wB2, x1, wG2, wB2l, d_out, flags);
}

// Round 8
// 336.401 us; speedup vs baseline: 1.0133x; 1.0133x over previous
//
#include <hip/hip_runtime.h>
#include <stdint.h>

typedef unsigned short u16;
typedef __bf16 bf16x8 __attribute__((ext_vector_type(8)));
typedef float f32x4 __attribute__((ext_vector_type(4)));

#define AS1(p) ((const __attribute__((address_space(1))) void*)(p))
#define AS3(p) ((__attribute__((address_space(3))) void*)(p))

__device__ __forceinline__ float b2f(u16 v){
    union { unsigned u; float f; } x; x.u = ((unsigned)v) << 16; return x.f;
}
__device__ __forceinline__ u16 f2b(float f){
    union { float f; unsigned u; } x; x.f = f;
    unsigned r = x.u + 0x7FFFu + ((x.u >> 16) & 1u);
    return (u16)(r >> 16);
}

// ---------------- dtype probe: one block per input tensor (unchanged, proven) ----------------
__global__ __launch_bounds__(256) void probe_kernel(
    const u16* p0,const u16* p1,const u16* p2,const u16* p3,const u16* p4,
    const u16* p5,const u16* p6,const u16* p7,const u16* p8,const u16* p9,
    const u16* p10,const u16* p11,const u16* p12,
    int n0,int n1,int n2,int n3,int n4,int n5,int n6,int n7,int n8,int n9,
    int n10,int n11,int n12, int* flags)
{
    const u16* p; int n;
    switch (blockIdx.x) {
        case 0: p=p0; n=n0; break;   case 1: p=p1; n=n1; break;
        case 2: p=p2; n=n2; break;   case 3: p=p3; n=n3; break;
        case 4: p=p4; n=n4; break;   case 5: p=p5; n=n5; break;
        case 6: p=p6; n=n6; break;   case 7: p=p7; n=n7; break;
        case 8: p=p8; n=n8; break;   case 9: p=p9; n=n9; break;
        case 10: p=p10; n=n10; break; case 11: p=p11; n=n11; break;
        default: p=p12; n=n12; break;
    }
    int pairs = n >> 1; if (pairs > 2048) pairs = 2048;
    int strong = 0, znz = 0, tot = 0;
    for (int k = threadIdx.x; k < pairs; k += 256) {
        u16 lo = p[2*k], hi = p[2*k+1];
        int eh = (hi >> 7) & 0xFF;
        int el = (lo >> 7) & 0xFF;
        if (eh >= 0xF0 || (eh >= 1 && eh <= 0x40)) strong = 1;
        if (el >= 0xF0 || (el >= 1 && el <= 0x40)) strong = 1;
        if (lo == 0 && hi != 0) znz++;
        tot++;
    }
    __shared__ int ss, sz, st;
    if (threadIdx.x == 0) { ss = 0; sz = 0; st = 0; }
    __syncthreads();
    if (strong) atomicOr(&ss, 1);
    if (znz) atomicAdd(&sz, znz);
    atomicAdd(&st, tot);
    __syncthreads();
    if (threadIdx.x == 0) {
        flags[blockIdx.x] = (ss || (2 * sz > st)) ? 1 : 0;
        if (blockIdx.x == 0) flags[15] = 0;
    }
}

// ---------------- convert weight/vector tensors to bf16 (Tf -> f32) in ws (unchanged) -----------
__global__ __launch_bounds__(256) void convert_kernel(
    const void* sWc, const void* sW2, const void* sW1,
    const void* sTa, const void* sBc, const void* sG1, const void* sB1l,
    const void* sTf, const void* sB1, const void* sB2, const void* sG2, const void* sB2l,
    u16* wbase, const int* flags)
{
    int b = blockIdx.x;
    const void* src; u16* dst; int n, fi, lb, tof32 = 0;
    if (b < 128)      { src=sWc; dst=wbase;          n=262144;  fi=2;  lb=b; }
    else if (b < 640) { src=sW2; dst=wbase+262144;   n=1048576; fi=9;  lb=b-128; }
    else if (b >= 643 && b < 651) { src=sW1; dst=wbase+1312256; n=16384; fi=7; lb=b-643; }
    else {
        lb = 0;
        switch (b) {
            case 640: src=sTa;  dst=wbase+1310720; n=512;  fi=1;  break;
            case 641: src=sBc;  dst=wbase+1311232; n=512;  fi=3;  break;
            case 642: src=sB2;  dst=wbase+1311744; n=512;  fi=10; break;
            case 651: src=sB1;  dst=wbase+1328640; n=2048; fi=8;  break;
            case 652: src=sG1;  dst=wbase+1330688; n=512;  fi=4;  break;
            case 653: src=sB1l; dst=wbase+1331200; n=512;  fi=5;  break;
            case 654: src=sG2;  dst=wbase+1331712; n=512;  fi=11; break;
            case 655: src=sB2l; dst=wbase+1332224; n=512;  fi=12; break;
            default:  src=sTf;  dst=wbase+1332736; n=8;    fi=6;  tof32=1; break;
        }
    }
    int i = lb * 256 + threadIdx.x;
    if (i * 8 >= n) return;
    if (tof32) {
        float* fd = (float*)dst;
        if (flags[fi]) {
            const float4* s = (const float4*)src;
            ((float4*)fd)[i*2] = s[i*2]; ((float4*)fd)[i*2+1] = s[i*2+1];
        } else {
            union { uint4 v; u16 h[8]; } sb;
            sb.v = ((const uint4*)src)[i];
            #pragma unroll
            for (int j = 0; j < 8; j++) fd[i*8+j] = b2f(sb.h[j]);
        }
        return;
    }
    if (flags[fi]) {
        const float4* s = (const float4*)src;
        float4 a = s[i*2], c = s[i*2+1];
        union { uint4 v; u16 h[8]; } o;
        o.h[0]=f2b(a.x); o.h[1]=f2b(a.y); o.h[2]=f2b(a.z); o.h[3]=f2b(a.w);
        o.h[4]=f2b(c.x); o.h[5]=f2b(c.y); o.h[6]=f2b(c.z); o.h[7]=f2b(c.w);
        ((uint4*)dst)[i] = o.v;
    } else {
        ((uint4*)dst)[i] = ((const uint4*)src)[i];
    }
}

// ---------------- qgen: q[m,k] = bf16(cos(x[m,k] + theta[k])) — pure streaming ----------------
__global__ __launch_bounds__(256) void qgen_kernel(
    const void* __restrict__ x, const u16* __restrict__ theta,
    u16* __restrict__ q, const int* flags)
{
    const int idx = blockIdx.x * 256 + threadIdx.x;   // octet index, 2,097,152 total
    const int col0 = (idx * 8) & 511;
    union { uint4 v; u16 h[8]; } tb;
    tb.v = *(const uint4*)(theta + col0);
    float xv[8];
    if (flags[0]) {
        const float4* p = (const float4*)x + idx * 2;
        float4 a = p[0], b = p[1];
        xv[0]=a.x; xv[1]=a.y; xv[2]=a.z; xv[3]=a.w;
        xv[4]=b.x; xv[5]=b.y; xv[6]=b.z; xv[7]=b.w;
    } else {
        union { uint4 v; u16 h[8]; } xb;
        xb.v = ((const uint4*)x)[idx];
        #pragma unroll
        for (int e = 0; e < 8; e++) xv[e] = b2f(xb.h[e]);
    }
    union { uint4 v; u16 h[8]; } o;
    #pragma unroll
    for (int e = 0; e < 8; e++) o.h[e] = f2b(__cosf(xv[e] + b2f(tb.h[e])));
    ((uint4*)q)[idx] = o.v;
}

// ======== gemm1: y1[m,n] = sum_k q[m,k]*Wc[n,k] + bc[n] + x[m,n] ========
// Pure bf16 GEMM, m97-family (unchanged — below gemm2 in the profile).
__global__ __launch_bounds__(256, 3) void gemm1_fused(
    const u16* __restrict__ q, const void* __restrict__ x,
    const u16* __restrict__ Wt, const u16* __restrict__ bias,
    u16* __restrict__ dst, int mtiles, const int* flags)
{
    __shared__ __align__(16) u16 As[2][128 * 64];
    __shared__ __align__(16) u16 Bs[2][128 * 64];
    const int K = 512, N = 512;
    const int tid  = threadIdx.x;
    const int lane = tid & 63;
    const int w    = tid >> 6;

    const int blk = blockIdx.x;
    const int xcd = blk & 7;
    const int j   = blk >> 3;
    const int per = mtiles >> 3;
    const int mt  = xcd * per + (j >> 2);
    const int nt  = j & 3;
    const int m0 = mt * 128;
    const int n0 = nt * 128;

    const int srow = lane >> 3;
    const int scol = ((lane & 7) ^ srow) * 8;
    const int wm = (w >> 1) * 64;
    const int wn = (w & 1) * 64;
    const int fr   = lane & 15;
    const int quad = lane >> 4;
    const int fx   = fr & 7;
    const int isf32 = flags[0];

    f32x4 acc[4][4];
    #pragma unroll
    for (int i = 0; i < 4; i++)
        #pragma unroll
        for (int jj = 0; jj < 4; jj++)
            acc[i][jj] = f32x4{0.f, 0.f, 0.f, 0.f};

    const u16* Abase = q  + (size_t)m0 * K + scol;
    const u16* Bbase = Wt + (size_t)n0 * K + scol;

    // prologue: stage buf 0 (A + B)
    #pragma unroll
    for (int i = 0; i < 4; i++) {
        int c = w * 4 + i;
        int row = c * 8 + srow;
        __builtin_amdgcn_global_load_lds(AS1(Abase + (size_t)row * K),
                                         AS3(&As[0][c * 512]), 16, 0, 0);
        __builtin_amdgcn_global_load_lds(AS1(Bbase + (size_t)row * K),
                                         AS3(&Bs[0][c * 512]), 16, 0, 0);
    }

    int cur = 0;
    for (int kt = 0; kt < K; kt += 64) {
        __syncthreads();               // buf[cur] staged (vmcnt drained at barrier)
        if (kt + 64 < K) {             // issue next-tile staging; flies under MFMA phase
            int nxt = cur ^ 1;
            #pragma unroll
            for (int i = 0; i < 4; i++) {
                int c = w * 4 + i;
                int row = c * 8 + srow;
                __builtin_amdgcn_global_load_lds(
                    AS1(Abase + (size_t)row * K + kt + 64),
                    AS3(&As[nxt][c * 512]), 16, 0, 0);
                __builtin_amdgcn_global_load_lds(
                    AS1(Bbase + (size_t)row * K + kt + 64),
                    AS3(&Bs[nxt][c * 512]), 16, 0, 0);
            }
        }
        #pragma unroll
        for (int kk = 0; kk < 2; kk++) {
            bf16x8 af[4], bfr[4];
            #pragma unroll
            for (int mi = 0; mi < 4; mi++)
                af[mi] = *(const bf16x8*)(&As[cur][(wm + mi * 16 + fr) * 64 +
                                          (((kk * 4 + quad) ^ fx) * 8)]);
            #pragma unroll
            for (int ni = 0; ni < 4; ni++)
                bfr[ni] = *(const bf16x8*)(&Bs[cur][(wn + ni * 16 + fr) * 64 +
                                           (((kk * 4 + quad) ^ fx) * 8)]);
            #pragma unroll
            for (int mi = 0; mi < 4; mi++)
                #pragma unroll
                for (int ni = 0; ni < 4; ni++)
                    acc[mi][ni] = __builtin_amdgcn_mfma_f32_16x16x32_bf16(
                        af[mi], bfr[ni], acc[mi][ni], 0, 0, 0);
        }
        cur ^= 1;
    }

    #pragma unroll
    for (int mi = 0; mi < 4; mi++) {
        #pragma unroll
        for (int ni = 0; ni < 4; ni++) {
            int n = n0 + wn + ni * 16 + fr;
            float bn = b2f(bias[n]);
            #pragma unroll
            for (int r = 0; r < 4; r++) {
                int m = m0 + wm + mi * 16 + quad * 4 + r;
                float rv = isf32 ? ((const float*)x)[(size_t)m * N + n]
                                 : b2f(((const u16*)x)[(size_t)m * N + n]);
                dst[(size_t)m * N + n] = f2b(acc[mi][ni][r] + bn + rv);
            }
        }
    }
}

// ======== gemm2 + fused LN2: out = LN(h@W2 + b2 + x1) ========
// R5 geometry: BM=128 x BN=512 x BK=64, 8 waves as 2m x 4n, wave = 64m x 128n,
// acc[4][8]. Register h-gen, Bs dbuf 128KB, 1 barrier/K-step, grid 256 = 1 block/CU.
// LN2 fused in the epilogue (saves z write+read 66MB + a dispatch; absmax improved).
// R7 POST-MORTEM: launch_bounds(512,2) capped unified regs at 256; acc(128 AGPR)+arch
// hit the cap -> ~85MB scratch spill traffic (WRITE 121MB, FETCH +30MB), gemm2 95->130us.
// FIX: (512,1) — LDS already limits to 1 block/CU, so the 256-cap bought nothing.
// Epilogue also restructured per-mi (peak temp liveness 8 regs, not 32).
__global__ __launch_bounds__(512, 1) void gemm2_fused(
    const u16* __restrict__ fq, const u16* __restrict__ W1, const u16* __restrict__ b1,
    const u16* __restrict__ Wt, const u16* __restrict__ bias,
    const u16* __restrict__ res, const u16* __restrict__ g2, const u16* __restrict__ b2l,
    void* __restrict__ out, const int* flags)
{
    __shared__ __align__(16) u16 Bs[2][512 * 64];
    const int K = 2048, N = 512;
    const int tid  = threadIdx.x;
    const int lane = tid & 63;
    const int w    = tid >> 6;

    const int m0 = blockIdx.x * 128;

    const int srow = lane >> 3;
    const int scol = ((lane & 7) ^ srow) * 8;
    const int wm = (w >> 2) * 64;          // 2 waves per 64-row m-range
    const int wn = (w & 3) * 128;          // 4 n-positions of 128
    const int fr   = lane & 15;
    const int quad = lane >> 4;
    const int fx   = fr & 7;
    const int isf32 = flags[0];

    // fq B-frags for h-gen: wave's own 4 m-subtiles (m = m0+wm+mi*16+fr), quad0 holds data.
    bf16x8 fqf[4];
    #pragma unroll
    for (int mi = 0; mi < 4; mi++) {
        union { uint4 v; bf16x8 b; } z; z.v = uint4{0,0,0,0};
        if (quad == 0) z.v = *(const uint4*)(fq + (size_t)(m0 + wm + mi * 16 + fr) * 8);
        fqf[mi] = z.b;
    }

    // interleaved W1-row index for h-gen MFMA g (quad0 lanes supply A rows):
    const int krow = ((fr >> 2) * 8) + (fr & 3);      // + kt + (g>>1)*32 + (g&1)*4

    // W1 frags + b1 frags for kt=0 (proven layout)
    union { uint4 v; bf16x8 b; } w1f[4];
    uint2 b1f[4];
    #pragma unroll
    for (int g = 0; g < 4; g++) {
        w1f[g].v = uint4{0,0,0,0};
        if (quad == 0)
            w1f[g].v = *(const uint4*)(W1 + (size_t)((g >> 1) * 32 + (g & 1) * 4 + krow) * 8);
        b1f[g] = *(const uint2*)(b1 + (g >> 1) * 32 + (g & 1) * 4 + quad * 8);
    }

    f32x4 acc[4][8];
    #pragma unroll
    for (int i = 0; i < 4; i++)
        #pragma unroll
        for (int jj = 0; jj < 8; jj++)
            acc[i][jj] = f32x4{0.f, 0.f, 0.f, 0.f};

    // B staging: rows are n (0..511), full N. 8 row-groups of 8 per wave-issue set.
    const u16* Bbase = Wt + scol;
    #pragma unroll
    for (int i = 0; i < 8; i++) {
        int c = w * 8 + i;
        int row = c * 8 + srow;
        __builtin_amdgcn_global_load_lds(AS1(Bbase + (size_t)row * K),
                                         AS3(&Bs[0][c * 512]), 16, 0, 0);
    }

    int cur = 0;
    for (int kt = 0; kt < K; kt += 64) {
        __syncthreads();               // Bs[cur] staged, w1f/b1f for this kt ready
        if (kt + 64 < K) {             // issue next Bs staging; flies under compute
            int nxt = cur ^ 1;
            #pragma unroll
            for (int i = 0; i < 8; i++) {
                int c = w * 8 + i;
                int row = c * 8 + srow;
                __builtin_amdgcn_global_load_lds(
                    AS1(Bbase + (size_t)row * K + kt + 64),
                    AS3(&Bs[nxt][c * 512]), 16, 0, 0);
            }
        }
        #pragma unroll
        for (int kk = 0; kk < 2; kk++) {
            // ---- h-gen: af for all 4 mi (register-direct, proven identity) ----
            const u16* pb0 = (const u16*)&b1f[kk * 2 + 0];
            const u16* pb1 = (const u16*)&b1f[kk * 2 + 1];
            f32x4 c0 = {b2f(pb0[0]), b2f(pb0[1]), b2f(pb0[2]), b2f(pb0[3])};
            f32x4 c1 = {b2f(pb1[0]), b2f(pb1[1]), b2f(pb1[2]), b2f(pb1[3])};
            bf16x8 af[4];
            #pragma unroll
            for (int mi = 0; mi < 4; mi++) {
                f32x4 hv0 = __builtin_amdgcn_mfma_f32_16x16x32_bf16(
                    w1f[kk * 2 + 0].b, fqf[mi], c0, 0, 0, 0);
                f32x4 hv1 = __builtin_amdgcn_mfma_f32_16x16x32_bf16(
                    w1f[kk * 2 + 1].b, fqf[mi], c1, 0, 0, 0);
                #pragma unroll
                for (int r = 0; r < 4; r++) {
                    af[mi][r]     = (__bf16)fmaxf(hv0[r], 0.f);
                    af[mi][4 + r] = (__bf16)fmaxf(hv1[r], 0.f);
                }
            }
            // ---- main MFMA over the wave's 128 n, bfr in PAIRS ----
            #pragma unroll
            for (int np = 0; np < 4; np++) {
                bf16x8 bfr[2];
                #pragma unroll
                for (int ni = 0; ni < 2; ni++)
                    bfr[ni] = *(const bf16x8*)(&Bs[cur][(wn + (np * 2 + ni) * 16 + fr) * 64 +
                                               (((kk * 4 + quad) ^ fx) * 8)]);
                #pragma unroll
                for (int mi = 0; mi < 4; mi++)
                    #pragma unroll
                    for (int ni = 0; ni < 2; ni++)
                        acc[mi][np * 2 + ni] = __builtin_amdgcn_mfma_f32_16x16x32_bf16(
                            af[mi], bfr[ni], acc[mi][np * 2 + ni], 0, 0, 0);
            }
        }
        // prefetch next kt's W1/b1 frags (tiny, L1/L2-resident)
        if (kt + 64 < K) {
            #pragma unroll
            for (int g = 0; g < 4; g++) {
                if (quad == 0)
                    w1f[g].v = *(const uint4*)(W1 +
                        (size_t)(kt + 64 + (g >> 1) * 32 + (g & 1) * 4 + krow) * 8);
                b1f[g] = *(const uint2*)(b1 + kt + 64 + (g >> 1) * 32 + (g & 1) * 4 + quad * 8);
            }
        }
        cur ^= 1;
    }

    // ================= fused LN2 epilogue (per-mi phases, low liveness) =================
    __syncthreads();                    // all waves done with Bs -> reuse as reduce scratch
    float2* red = (float2*)(&Bs[0][0]); // [row 0..127][wnIdx 0..3]

    #pragma unroll
    for (int mi = 0; mi < 4; mi++) {
        float s[4] = {0.f, 0.f, 0.f, 0.f};
        float sq[4] = {0.f, 0.f, 0.f, 0.f};
        #pragma unroll
        for (int nq = 0; nq < 8; nq++) {
            int n = wn + nq * 16 + fr;
            float bn = b2f(bias[n]);
            #pragma unroll
            for (int r = 0; r < 4; r++) {
                int m = m0 + wm + mi * 16 + quad * 4 + r;
                float v = acc[mi][nq][r] + bn + b2f(res[(size_t)m * N + n]);
                acc[mi][nq][r] = v;
                s[r] += v; sq[r] += v * v;
            }
        }
        #pragma unroll
        for (int o = 1; o < 16; o <<= 1) {
            #pragma unroll
            for (int r = 0; r < 4; r++) {
                s[r]  += __shfl_xor(s[r],  o);
                sq[r] += __shfl_xor(sq[r], o);
            }
        }
        if (fr == 0) {
            #pragma unroll
            for (int r = 0; r < 4; r++) {
                int row = wm + mi * 16 + quad * 4 + r;
                red[row * 4 + (w & 3)] = float2{s[r], sq[r]};
            }
        }
    }
    __syncthreads();

    #pragma unroll
    for (int mi = 0; mi < 4; mi++) {
        float mu[4], rs[4];
        #pragma unroll
        for (int r = 0; r < 4; r++) {
            int row = wm + mi * 16 + quad * 4 + r;
            float S = 0.f, SS = 0.f;
            #pragma unroll
            for (int jj = 0; jj < 4; jj++) {
                float2 p = red[row * 4 + jj];
                S += p.x; SS += p.y;
            }
            float m_ = S * (1.f / 512.f);
            mu[r] = m_;
            rs[r] = rsqrtf(SS * (1.f / 512.f) - m_ * m_ + 1e-5f);
        }
        #pragma unroll
        for (int nq = 0; nq < 8; nq++) {
            int n = wn + nq * 16 + fr;
            float gv = b2f(g2[n]);
            float bv = b2f(b2l[n]);
            #pragma unroll
            for (int r = 0; r < 4; r++) {
                int m = m0 + wm + mi * 16 + quad * 4 + r;
                float val = (acc[mi][nq][r] - mu[r]) * rs[r] * gv + bv;
                if (isf32) ((float*)out)[(size_t)m * N + n] = val;
                else       ((u16*)out)[(size_t)m * N + n] = f2b(val);
            }
        }
    }
}

// ------- ln1: x1 = LN(y1)*g+b; fq = cos(x1[:,:8]+tf)  (h generation stays in gemm2) -------
__global__ __launch_bounds__(512) void ln1_kernel(
    const u16* __restrict__ y1, const u16* __restrict__ g, const u16* __restrict__ b,
    const float* __restrict__ tf, u16* __restrict__ x1, u16* __restrict__ fqout)
{
    __shared__ __align__(16) float xs8[64][8];
    const int t = threadIdx.x;
    const int wv = t >> 6, l = t & 63;
    const size_t rbase = (size_t)blockIdx.x * 64;

    union { uint4 v; u16 s[8]; } gb, bb;
    gb.v = *(const uint4*)(g + l * 8);
    bb.v = *(const uint4*)(b + l * 8);

    #pragma unroll
    for (int i = 0; i < 8; i++) {
        int lr = wv * 8 + i;
        union { uint4 v; u16 s[8]; } yb;
        yb.v = ((const uint4*)(y1 + (rbase + lr) * 512))[l];
        float xv[8], s = 0.f, ss = 0.f;
        #pragma unroll
        for (int jj = 0; jj < 8; jj++) {
            xv[jj] = b2f(yb.s[jj]); s += xv[jj]; ss += xv[jj] * xv[jj];
        }
        #pragma unroll
        for (int o = 32; o > 0; o >>= 1) { s += __shfl_down(s, o); ss += __shfl_down(ss, o); }
        s = __shfl(s, 0); ss = __shfl(ss, 0);
        float mu = s * (1.f / 512.f);
        float rs = rsqrtf(ss * (1.f / 512.f) - mu * mu + 1e-5f);
        union { uint4 v; u16 s[8]; } ob;
        float xn[8];
        #pragma unroll
        for (int jj = 0; jj < 8; jj++) {
            xn[jj] = (xv[jj] - mu) * rs * b2f(gb.s[jj]) + b2f(bb.s[jj]);
            ob.s[jj] = f2b(xn[jj]);
        }
        ((uint4*)(x1 + (rbase + lr) * 512))[l] = ob.v;
        if (l == 0) {
            #pragma unroll
            for (int jj = 0; jj < 8; jj++) xs8[lr][jj] = xn[jj];
        }
    }
    __syncthreads();
    {
        int r = t >> 3, jj = t & 7;
        fqout[(rbase + r) * 8 + jj] = f2b(__cosf(xs8[r][jj] + tf[jj]));
    }
}

extern "C" void kernel_launch(void* const* d_in, const int* in_sizes, int n_in,
                              void* d_out, int out_size, void* d_ws, size_t ws_size,
                              hipStream_t stream)
{
    u16* ws16 = (u16*)d_ws;
    // ws (u16 elems): W [0,1332752) | flags @1332752 | fq @1332800 (262144)
    //                 x1 @1594944 (16.7M) | y1 @18372160 (16.7M)
    // q (cos(x+theta), bf16) ALIASES the x1 region: q live [qgen, gemm1); x1 written by ln1 after.
    // z is never materialized: LN2 fused into gemm2's epilogue -> writes d_out directly.
    u16* W     = ws16;
    int* flags = (int*)(ws16 + 1332752);
    u16* fq  = ws16 + 1332800;
    u16* x1  = ws16 + 1594944;
    u16* q   = x1;
    u16* y1  = ws16 + 18372160;

    const u16*  wWc  = W;
    const u16*  wW2  = W + 262144;
    const u16*  wTa  = W + 1310720;
    const u16*  wBc  = W + 1311232;
    const u16*  wB2  = W + 1311744;
    const u16*  wW1  = W + 1312256;
    const u16*  wB1  = W + 1328640;
    const u16*  wG1  = W + 1330688;
    const u16*  wB1l = W + 1331200;
    const u16*  wG2  = W + 1331712;
    const u16*  wB2l = W + 1332224;
    const float* wTf = (const float*)(W + 1332736);

    probe_kernel<<<13, 256, 0, stream>>>(
        (const u16*)d_in[0], (const u16*)d_in[1], (const u16*)d_in[2],
        (const u16*)d_in[3], (const u16*)d_in[4], (const u16*)d_in[5],
        (const u16*)d_in[6], (const u16*)d_in[7], (const u16*)d_in[8],
        (const u16*)d_in[9], (const u16*)d_in[10], (const u16*)d_in[11],
        (const u16*)d_in[12],
        in_sizes[0], in_sizes[1], in_sizes[2], in_sizes[3], in_sizes[4],
        in_sizes[5], in_sizes[6], in_sizes[7], in_sizes[8], in_sizes[9],
        in_sizes[10], in_sizes[11], in_sizes[12], flags);

    convert_kernel<<<657, 256, 0, stream>>>(
        d_in[2], d_in[9], d_in[7], d_in[1], d_in[3], d_in[4], d_in[5],
        d_in[6], d_in[8], d_in[10], d_in[11], d_in[12], (u16*)W, flags);

    qgen_kernel<<<8192, 256, 0, stream>>>(d_in[0], wTa, q, flags);

    gemm1_fused<<<1024, 256, 0, stream>>>(
        q, d_in[0], wWc, wBc, y1, 256, flags);

    ln1_kernel<<<512, 512, 0, stream>>>(y1, wG1, wB1l, wTf, x1, fq);

    gemm2_fused<<<256, 512, 0, stream>>>(
        fq, wW1, wB1, wW2, wB2, x1, wG2, wB2l, d_out, flags);
}

// Round 9
// 306.290 us; speedup vs baseline: 1.1129x; 1.0983x over previous
//
#include <hip/hip_runtime.h>
#include <stdint.h>

typedef unsigned short u16;
typedef __bf16 bf16x8 __attribute__((ext_vector_type(8)));
typedef float f32x4 __attribute__((ext_vector_type(4)));

#define AS1(p) ((const __attribute__((address_space(1))) void*)(p))
#define AS3(p) ((__attribute__((address_space(3))) void*)(p))

__device__ __forceinline__ float b2f(u16 v){
    union { unsigned u; float f; } x; x.u = ((unsigned)v) << 16; return x.f;
}
__device__ __forceinline__ u16 f2b(float f){
    union { float f; unsigned u; } x; x.f = f;
    unsigned r = x.u + 0x7FFFu + ((x.u >> 16) & 1u);
    return (u16)(r >> 16);
}

// ---------------- dtype probe: one block per input tensor (unchanged, proven) ----------------
__global__ __launch_bounds__(256) void probe_kernel(
    const u16* p0,const u16* p1,const u16* p2,const u16* p3,const u16* p4,
    const u16* p5,const u16* p6,const u16* p7,const u16* p8,const u16* p9,
    const u16* p10,const u16* p11,const u16* p12,
    int n0,int n1,int n2,int n3,int n4,int n5,int n6,int n7,int n8,int n9,
    int n10,int n11,int n12, int* flags)
{
    const u16* p; int n;
    switch (blockIdx.x) {
        case 0: p=p0; n=n0; break;   case 1: p=p1; n=n1; break;
        case 2: p=p2; n=n2; break;   case 3: p=p3; n=n3; break;
        case 4: p=p4; n=n4; break;   case 5: p=p5; n=n5; break;
        case 6: p=p6; n=n6; break;   case 7: p=p7; n=n7; break;
        case 8: p=p8; n=n8; break;   case 9: p=p9; n=n9; break;
        case 10: p=p10; n=n10; break; case 11: p=p11; n=n11; break;
        default: p=p12; n=n12; break;
    }
    int pairs = n >> 1; if (pairs > 2048) pairs = 2048;
    int strong = 0, znz = 0, tot = 0;
    for (int k = threadIdx.x; k < pairs; k += 256) {
        u16 lo = p[2*k], hi = p[2*k+1];
        int eh = (hi >> 7) & 0xFF;
        int el = (lo >> 7) & 0xFF;
        if (eh >= 0xF0 || (eh >= 1 && eh <= 0x40)) strong = 1;
        if (el >= 0xF0 || (el >= 1 && el <= 0x40)) strong = 1;
        if (lo == 0 && hi != 0) znz++;
        tot++;
    }
    __shared__ int ss, sz, st;
    if (threadIdx.x == 0) { ss = 0; sz = 0; st = 0; }
    __syncthreads();
    if (strong) atomicOr(&ss, 1);
    if (znz) atomicAdd(&sz, znz);
    atomicAdd(&st, tot);
    __syncthreads();
    if (threadIdx.x == 0) {
        flags[blockIdx.x] = (ss || (2 * sz > st)) ? 1 : 0;
        if (blockIdx.x == 0) flags[15] = 0;
    }
}

// ---------------- convert weight/vector tensors to bf16 (Tf -> f32) in ws (unchanged) -----------
__global__ __launch_bounds__(256) void convert_kernel(
    const void* sWc, const void* sW2, const void* sW1,
    const void* sTa, const void* sBc, const void* sG1, const void* sB1l,
    const void* sTf, const void* sB1, const void* sB2, const void* sG2, const void* sB2l,
    u16* wbase, const int* flags)
{
    int b = blockIdx.x;
    const void* src; u16* dst; int n, fi, lb, tof32 = 0;
    if (b < 128)      { src=sWc; dst=wbase;          n=262144;  fi=2;  lb=b; }
    else if (b < 640) { src=sW2; dst=wbase+262144;   n=1048576; fi=9;  lb=b-128; }
    else if (b >= 643 && b < 651) { src=sW1; dst=wbase+1312256; n=16384; fi=7; lb=b-643; }
    else {
        lb = 0;
        switch (b) {
            case 640: src=sTa;  dst=wbase+1310720; n=512;  fi=1;  break;
            case 641: src=sBc;  dst=wbase+1311232; n=512;  fi=3;  break;
            case 642: src=sB2;  dst=wbase+1311744; n=512;  fi=10; break;
            case 651: src=sB1;  dst=wbase+1328640; n=2048; fi=8;  break;
            case 652: src=sG1;  dst=wbase+1330688; n=512;  fi=4;  break;
            case 653: src=sB1l; dst=wbase+1331200; n=512;  fi=5;  break;
            case 654: src=sG2;  dst=wbase+1331712; n=512;  fi=11; break;
            case 655: src=sB2l; dst=wbase+1332224; n=512;  fi=12; break;
            default:  src=sTf;  dst=wbase+1332736; n=8;    fi=6;  tof32=1; break;
        }
    }
    int i = lb * 256 + threadIdx.x;
    if (i * 8 >= n) return;
    if (tof32) {
        float* fd = (float*)dst;
        if (flags[fi]) {
            const float4* s = (const float4*)src;
            ((float4*)fd)[i*2] = s[i*2]; ((float4*)fd)[i*2+1] = s[i*2+1];
        } else {
            union { uint4 v; u16 h[8]; } sb;
            sb.v = ((const uint4*)src)[i];
            #pragma unroll
            for (int j = 0; j < 8; j++) fd[i*8+j] = b2f(sb.h[j]);
        }
        return;
    }
    if (flags[fi]) {
        const float4* s = (const float4*)src;
        float4 a = s[i*2], c = s[i*2+1];
        union { uint4 v; u16 h[8]; } o;
        o.h[0]=f2b(a.x); o.h[1]=f2b(a.y); o.h[2]=f2b(a.z); o.h[3]=f2b(a.w);
        o.h[4]=f2b(c.x); o.h[5]=f2b(c.y); o.h[6]=f2b(c.z); o.h[7]=f2b(c.w);
        ((uint4*)dst)[i] = o.v;
    } else {
        ((uint4*)dst)[i] = ((const uint4*)src)[i];
    }
}

// ---------------- qgen: q[m,k] = bf16(cos(x[m,k] + theta[k])) — pure streaming ----------------
__global__ __launch_bounds__(256) void qgen_kernel(
    const void* __restrict__ x, const u16* __restrict__ theta,
    u16* __restrict__ q, const int* flags)
{
    const int idx = blockIdx.x * 256 + threadIdx.x;   // octet index, 2,097,152 total
    const int col0 = (idx * 8) & 511;
    union { uint4 v; u16 h[8]; } tb;
    tb.v = *(const uint4*)(theta + col0);
    float xv[8];
    if (flags[0]) {
        const float4* p = (const float4*)x + idx * 2;
        float4 a = p[0], b = p[1];
        xv[0]=a.x; xv[1]=a.y; xv[2]=a.z; xv[3]=a.w;
        xv[4]=b.x; xv[5]=b.y; xv[6]=b.z; xv[7]=b.w;
    } else {
        union { uint4 v; u16 h[8]; } xb;
        xb.v = ((const uint4*)x)[idx];
        #pragma unroll
        for (int e = 0; e < 8; e++) xv[e] = b2f(xb.h[e]);
    }
    union { uint4 v; u16 h[8]; } o;
    #pragma unroll
    for (int e = 0; e < 8; e++) o.h[e] = f2b(__cosf(xv[e] + b2f(tb.h[e])));
    ((uint4*)q)[idx] = o.v;
}

// ======== gemm1: y1[m,n] = sum_k q[m,k]*Wc[n,k] + bc[n] + x[m,n] ========
// Pure bf16 GEMM, m97-family (unchanged — below gemm2 in the profile).
__global__ __launch_bounds__(256, 3) void gemm1_fused(
    const u16* __restrict__ q, const void* __restrict__ x,
    const u16* __restrict__ Wt, const u16* __restrict__ bias,
    u16* __restrict__ dst, int mtiles, const int* flags)
{
    __shared__ __align__(16) u16 As[2][128 * 64];
    __shared__ __align__(16) u16 Bs[2][128 * 64];
    const int K = 512, N = 512;
    const int tid  = threadIdx.x;
    const int lane = tid & 63;
    const int w    = tid >> 6;

    const int blk = blockIdx.x;
    const int xcd = blk & 7;
    const int j   = blk >> 3;
    const int per = mtiles >> 3;
    const int mt  = xcd * per + (j >> 2);
    const int nt  = j & 3;
    const int m0 = mt * 128;
    const int n0 = nt * 128;

    const int srow = lane >> 3;
    const int scol = ((lane & 7) ^ srow) * 8;
    const int wm = (w >> 1) * 64;
    const int wn = (w & 1) * 64;
    const int fr   = lane & 15;
    const int quad = lane >> 4;
    const int fx   = fr & 7;
    const int isf32 = flags[0];

    f32x4 acc[4][4];
    #pragma unroll
    for (int i = 0; i < 4; i++)
        #pragma unroll
        for (int jj = 0; jj < 4; jj++)
            acc[i][jj] = f32x4{0.f, 0.f, 0.f, 0.f};

    const u16* Abase = q  + (size_t)m0 * K + scol;
    const u16* Bbase = Wt + (size_t)n0 * K + scol;

    // prologue: stage buf 0 (A + B)
    #pragma unroll
    for (int i = 0; i < 4; i++) {
        int c = w * 4 + i;
        int row = c * 8 + srow;
        __builtin_amdgcn_global_load_lds(AS1(Abase + (size_t)row * K),
                                         AS3(&As[0][c * 512]), 16, 0, 0);
        __builtin_amdgcn_global_load_lds(AS1(Bbase + (size_t)row * K),
                                         AS3(&Bs[0][c * 512]), 16, 0, 0);
    }

    int cur = 0;
    for (int kt = 0; kt < K; kt += 64) {
        __syncthreads();               // buf[cur] staged (vmcnt drained at barrier)
        if (kt + 64 < K) {             // issue next-tile staging; flies under MFMA phase
            int nxt = cur ^ 1;
            #pragma unroll
            for (int i = 0; i < 4; i++) {
                int c = w * 4 + i;
                int row = c * 8 + srow;
                __builtin_amdgcn_global_load_lds(
                    AS1(Abase + (size_t)row * K + kt + 64),
                    AS3(&As[nxt][c * 512]), 16, 0, 0);
                __builtin_amdgcn_global_load_lds(
                    AS1(Bbase + (size_t)row * K + kt + 64),
                    AS3(&Bs[nxt][c * 512]), 16, 0, 0);
            }
        }
        #pragma unroll
        for (int kk = 0; kk < 2; kk++) {
            bf16x8 af[4], bfr[4];
            #pragma unroll
            for (int mi = 0; mi < 4; mi++)
                af[mi] = *(const bf16x8*)(&As[cur][(wm + mi * 16 + fr) * 64 +
                                          (((kk * 4 + quad) ^ fx) * 8)]);
            #pragma unroll
            for (int ni = 0; ni < 4; ni++)
                bfr[ni] = *(const bf16x8*)(&Bs[cur][(wn + ni * 16 + fr) * 64 +
                                           (((kk * 4 + quad) ^ fx) * 8)]);
            #pragma unroll
            for (int mi = 0; mi < 4; mi++)
                #pragma unroll
                for (int ni = 0; ni < 4; ni++)
                    acc[mi][ni] = __builtin_amdgcn_mfma_f32_16x16x32_bf16(
                        af[mi], bfr[ni], acc[mi][ni], 0, 0, 0);
        }
        cur ^= 1;
    }

    #pragma unroll
    for (int mi = 0; mi < 4; mi++) {
        #pragma unroll
        for (int ni = 0; ni < 4; ni++) {
            int n = n0 + wn + ni * 16 + fr;
            float bn = b2f(bias[n]);
            #pragma unroll
            for (int r = 0; r < 4; r++) {
                int m = m0 + wm + mi * 16 + quad * 4 + r;
                float rv = isf32 ? ((const float*)x)[(size_t)m * N + n]
                                 : b2f(((const u16*)x)[(size_t)m * N + n]);
                dst[(size_t)m * N + n] = f2b(acc[mi][ni][r] + bn + rv);
            }
        }
    }
}

// ======== gemm2 + fused LN2: out = LN(h@W2 + b2 + x1) ========
// Main loop = R5 exact (proven: VGPR 124 + 128 acc = 252, NO spill).
// R7/R8 LESSON: a 512-thread block always has >=2 waves/SIMD -> 256-reg HARD cap;
// any in-register LN epilogue that keeps acc[4][8] live while streaming res/g2/b2l
// overflows it -> ~40-55MB scratch spill. FIX: phase-decoupled epilogue —
//   (1) barrier; fold bias+res into acc, f2b -> dump z tile [128][512] bf16 into Bs
//       (128KB, exactly the idle double buffer). acc DIES here.
//   (2) barrier; fresh LN phase: each wave owns 16 complete rows in LDS (ln2 kernel
//       verbatim, LDS-sourced) -> store d_out. Fresh ~30-reg working set, no acc.
// Numerics identical to the original z->ln2 path (z rounded to bf16 before LN).
__global__ __launch_bounds__(512, 2) void gemm2_fused(
    const u16* __restrict__ fq, const u16* __restrict__ W1, const u16* __restrict__ b1,
    const u16* __restrict__ Wt, const u16* __restrict__ bias,
    const u16* __restrict__ res, const u16* __restrict__ g2, const u16* __restrict__ b2l,
    void* __restrict__ out, const int* flags)
{
    __shared__ __align__(16) u16 Bs[2][512 * 64];
    const int K = 2048, N = 512;
    const int tid  = threadIdx.x;
    const int lane = tid & 63;
    const int w    = tid >> 6;

    const int m0 = blockIdx.x * 128;

    const int srow = lane >> 3;
    const int scol = ((lane & 7) ^ srow) * 8;
    const int wm = (w >> 2) * 64;          // 2 waves per 64-row m-range
    const int wn = (w & 3) * 128;          // 4 n-positions of 128
    const int fr   = lane & 15;
    const int quad = lane >> 4;
    const int fx   = fr & 7;
    const int isf32 = flags[0];

    // fq B-frags for h-gen: wave's own 4 m-subtiles (m = m0+wm+mi*16+fr), quad0 holds data.
    bf16x8 fqf[4];
    #pragma unroll
    for (int mi = 0; mi < 4; mi++) {
        union { uint4 v; bf16x8 b; } z; z.v = uint4{0,0,0,0};
        if (quad == 0) z.v = *(const uint4*)(fq + (size_t)(m0 + wm + mi * 16 + fr) * 8);
        fqf[mi] = z.b;
    }

    // interleaved W1-row index for h-gen MFMA g (quad0 lanes supply A rows):
    const int krow = ((fr >> 2) * 8) + (fr & 3);      // + kt + (g>>1)*32 + (g&1)*4

    // W1 frags + b1 frags for kt=0 (proven layout)
    union { uint4 v; bf16x8 b; } w1f[4];
    uint2 b1f[4];
    #pragma unroll
    for (int g = 0; g < 4; g++) {
        w1f[g].v = uint4{0,0,0,0};
        if (quad == 0)
            w1f[g].v = *(const uint4*)(W1 + (size_t)((g >> 1) * 32 + (g & 1) * 4 + krow) * 8);
        b1f[g] = *(const uint2*)(b1 + (g >> 1) * 32 + (g & 1) * 4 + quad * 8);
    }

    f32x4 acc[4][8];
    #pragma unroll
    for (int i = 0; i < 4; i++)
        #pragma unroll
        for (int jj = 0; jj < 8; jj++)
            acc[i][jj] = f32x4{0.f, 0.f, 0.f, 0.f};

    // B staging: rows are n (0..511), full N. 8 row-groups of 8 per wave-issue set.
    const u16* Bbase = Wt + scol;
    #pragma unroll
    for (int i = 0; i < 8; i++) {
        int c = w * 8 + i;
        int row = c * 8 + srow;
        __builtin_amdgcn_global_load_lds(AS1(Bbase + (size_t)row * K),
                                         AS3(&Bs[0][c * 512]), 16, 0, 0);
    }

    int cur = 0;
    for (int kt = 0; kt < K; kt += 64) {
        __syncthreads();               // Bs[cur] staged, w1f/b1f for this kt ready
        if (kt + 64 < K) {             // issue next Bs staging; flies under compute
            int nxt = cur ^ 1;
            #pragma unroll
            for (int i = 0; i < 8; i++) {
                int c = w * 8 + i;
                int row = c * 8 + srow;
                __builtin_amdgcn_global_load_lds(
                    AS1(Bbase + (size_t)row * K + kt + 64),
                    AS3(&Bs[nxt][c * 512]), 16, 0, 0);
            }
        }
        #pragma unroll
        for (int kk = 0; kk < 2; kk++) {
            // ---- h-gen: af for all 4 mi (register-direct, proven identity) ----
            const u16* pb0 = (const u16*)&b1f[kk * 2 + 0];
            const u16* pb1 = (const u16*)&b1f[kk * 2 + 1];
            f32x4 c0 = {b2f(pb0[0]), b2f(pb0[1]), b2f(pb0[2]), b2f(pb0[3])};
            f32x4 c1 = {b2f(pb1[0]), b2f(pb1[1]), b2f(pb1[2]), b2f(pb1[3])};
            bf16x8 af[4];
            #pragma unroll
            for (int mi = 0; mi < 4; mi++) {
                f32x4 hv0 = __builtin_amdgcn_mfma_f32_16x16x32_bf16(
                    w1f[kk * 2 + 0].b, fqf[mi], c0, 0, 0, 0);
                f32x4 hv1 = __builtin_amdgcn_mfma_f32_16x16x32_bf16(
                    w1f[kk * 2 + 1].b, fqf[mi], c1, 0, 0, 0);
                #pragma unroll
                for (int r = 0; r < 4; r++) {
                    af[mi][r]     = (__bf16)fmaxf(hv0[r], 0.f);
                    af[mi][4 + r] = (__bf16)fmaxf(hv1[r], 0.f);
                }
            }
            // ---- main MFMA over the wave's 128 n, bfr in PAIRS ----
            #pragma unroll
            for (int np = 0; np < 4; np++) {
                bf16x8 bfr[2];
                #pragma unroll
                for (int ni = 0; ni < 2; ni++)
                    bfr[ni] = *(const bf16x8*)(&Bs[cur][(wn + (np * 2 + ni) * 16 + fr) * 64 +
                                               (((kk * 4 + quad) ^ fx) * 8)]);
                #pragma unroll
                for (int mi = 0; mi < 4; mi++)
                    #pragma unroll
                    for (int ni = 0; ni < 2; ni++)
                        acc[mi][np * 2 + ni] = __builtin_amdgcn_mfma_f32_16x16x32_bf16(
                            af[mi], bfr[ni], acc[mi][np * 2 + ni], 0, 0, 0);
            }
        }
        // prefetch next kt's W1/b1 frags (tiny, L1/L2-resident)
        if (kt + 64 < K) {
            #pragma unroll
            for (int g = 0; g < 4; g++) {
                if (quad == 0)
                    w1f[g].v = *(const uint4*)(W1 +
                        (size_t)(kt + 64 + (g >> 1) * 32 + (g & 1) * 4 + krow) * 8);
                b1f[g] = *(const uint2*)(b1 + kt + 64 + (g >> 1) * 32 + (g & 1) * 4 + quad * 8);
            }
        }
        cur ^= 1;
    }

    // ============ phase 1: dump z = bf16(acc + b2 + res) into LDS [128][512] ============
    __syncthreads();                    // all waves done reading Bs
    u16* zt = &Bs[0][0];                // 128 rows x 512 cols bf16 = 128 KB
    #pragma unroll
    for (int mi = 0; mi < 4; mi++) {
        #pragma unroll
        for (int nq = 0; nq < 8; nq++) {
            int n = wn + nq * 16 + fr;
            float bn = b2f(bias[n]);
            #pragma unroll
            for (int r = 0; r < 4; r++) {
                int lm = wm + mi * 16 + quad * 4 + r;
                float v = acc[mi][nq][r] + bn + b2f(res[(size_t)(m0 + lm) * N + n]);
                zt[lm * 512 + n] = f2b(v);
            }
        }
    }
    __syncthreads();                    // z tile complete; acc dead

    // ============ phase 2: LN over complete rows in LDS (ln2 verbatim) ============
    {
        union { uint4 v; u16 s[8]; } gb, bb;
        gb.v = *(const uint4*)(g2 + lane * 8);
        bb.v = *(const uint4*)(b2l + lane * 8);
        for (int i = 0; i < 16; i++) {
            int row = w * 16 + i;
            union { uint4 v; u16 s[8]; } zb;
            zb.v = ((const uint4*)(zt + row * 512))[lane];
            float xv[8], s = 0.f, ss = 0.f;
            #pragma unroll
            for (int jj = 0; jj < 8; jj++) {
                xv[jj] = b2f(zb.s[jj]); s += xv[jj]; ss += xv[jj] * xv[jj];
            }
            #pragma unroll
            for (int o = 32; o > 0; o >>= 1) { s += __shfl_down(s, o); ss += __shfl_down(ss, o); }
            s = __shfl(s, 0); ss = __shfl(ss, 0);
            float mu = s * (1.f / 512.f);
            float rs = rsqrtf(ss * (1.f / 512.f) - mu * mu + 1e-5f);
            size_t m = (size_t)(m0 + row);
            if (isf32) {
                float xn[8];
                #pragma unroll
                for (int jj = 0; jj < 8; jj++)
                    xn[jj] = (xv[jj] - mu) * rs * b2f(gb.s[jj]) + b2f(bb.s[jj]);
                float* po = (float*)out + m * N + lane * 8;
                *(float4*)po       = float4{xn[0], xn[1], xn[2], xn[3]};
                *(float4*)(po + 4) = float4{xn[4], xn[5], xn[6], xn[7]};
            } else {
                union { uint4 v; u16 s[8]; } ob;
                #pragma unroll
                for (int jj = 0; jj < 8; jj++)
                    ob.s[jj] = f2b((xv[jj] - mu) * rs * b2f(gb.s[jj]) + b2f(bb.s[jj]));
                ((uint4*)((u16*)out + m * N))[lane] = ob.v;
            }
        }
    }
}

// ------- ln1: x1 = LN(y1)*g+b; fq = cos(x1[:,:8]+tf)  (h generation stays in gemm2) -------
__global__ __launch_bounds__(512) void ln1_kernel(
    const u16* __restrict__ y1, const u16* __restrict__ g, const u16* __restrict__ b,
    const float* __restrict__ tf, u16* __restrict__ x1, u16* __restrict__ fqout)
{
    __shared__ __align__(16) float xs8[64][8];
    const int t = threadIdx.x;
    const int wv = t >> 6, l = t & 63;
    const size_t rbase = (size_t)blockIdx.x * 64;

    union { uint4 v; u16 s[8]; } gb, bb;
    gb.v = *(const uint4*)(g + l * 8);
    bb.v = *(const uint4*)(b + l * 8);

    #pragma unroll
    for (int i = 0; i < 8; i++) {
        int lr = wv * 8 + i;
        union { uint4 v; u16 s[8]; } yb;
        yb.v = ((const uint4*)(y1 + (rbase + lr) * 512))[l];
        float xv[8], s = 0.f, ss = 0.f;
        #pragma unroll
        for (int jj = 0; jj < 8; jj++) {
            xv[jj] = b2f(yb.s[jj]); s += xv[jj]; ss += xv[jj] * xv[jj];
        }
        #pragma unroll
        for (int o = 32; o > 0; o >>= 1) { s += __shfl_down(s, o); ss += __shfl_down(ss, o); }
        s = __shfl(s, 0); ss = __shfl(ss, 0);
        float mu = s * (1.f / 512.f);
        float rs = rsqrtf(ss * (1.f / 512.f) - mu * mu + 1e-5f);
        union { uint4 v; u16 s[8]; } ob;
        float xn[8];
        #pragma unroll
        for (int jj = 0; jj < 8; jj++) {
            xn[jj] = (xv[jj] - mu) * rs * b2f(gb.s[jj]) + b2f(bb.s[jj]);
            ob.s[jj] = f2b(xn[jj]);
        }
        ((uint4*)(x1 + (rbase + lr) * 512))[l] = ob.v;
        if (l == 0) {
            #pragma unroll
            for (int jj = 0; jj < 8; jj++) xs8[lr][jj] = xn[jj];
        }
    }
    __syncthreads();
    {
        int r = t >> 3, jj = t & 7;
        fqout[(rbase + r) * 8 + jj] = f2b(__cosf(xs8[r][jj] + tf[jj]));
    }
}

extern "C" void kernel_launch(void* const* d_in, const int* in_sizes, int n_in,
                              void* d_out, int out_size, void* d_ws, size_t ws_size,
                              hipStream_t stream)
{
    u16* ws16 = (u16*)d_ws;
    // ws (u16 elems): W [0,1332752) | flags @1332752 | fq @1332800 (262144)
    //                 x1 @1594944 (16.7M) | y1 @18372160 (16.7M)
    // q (cos(x+theta), bf16) ALIASES the x1 region: q live [qgen, gemm1); x1 written by ln1 after.
    // z is never materialized: LN2 fused into gemm2's epilogue -> writes d_out directly.
    u16* W     = ws16;
    int* flags = (int*)(ws16 + 1332752);
    u16* fq  = ws16 + 1332800;
    u16* x1  = ws16 + 1594944;
    u16* q   = x1;
    u16* y1  = ws16 + 18372160;

    const u16*  wWc  = W;
    const u16*  wW2  = W + 262144;
    const u16*  wTa  = W + 1310720;
    const u16*  wBc  = W + 1311232;
    const u16*  wB2  = W + 1311744;
    const u16*  wW1  = W + 1312256;
    const u16*  wB1  = W + 1328640;
    const u16*  wG1  = W + 1330688;
    const u16*  wB1l = W + 1331200;
    const u16*  wG2  = W + 1331712;
    const u16*  wB2l = W + 1332224;
    const float* wTf = (const float*)(W + 1332736);

    probe_kernel<<<13, 256, 0, stream>>>(
        (const u16*)d_in[0], (const u16*)d_in[1], (const u16*)d_in[2],
        (const u16*)d_in[3], (const u16*)d_in[4], (const u16*)d_in[5],
        (const u16*)d_in[6], (const u16*)d_in[7], (const u16*)d_in[8],
        (const u16*)d_in[9], (const u16*)d_in[10], (const u16*)d_in[11],
        (const u16*)d_in[12],
        in_sizes[0], in_sizes[1], in_sizes[2], in_sizes[3], in_sizes[4],
        in_sizes[5], in_sizes[6], in_sizes[7], in_sizes[8], in_sizes[9],
        in_sizes[10], in_sizes[11], in_sizes[12], flags);

    convert_kernel<<<657, 256, 0, stream>>>(
        d_in[2], d_in[9], d_in[7], d_in[1], d_in[3], d_in[4], d_in[5],
        d_in[6], d_in[8], d_in[10], d_in[11], d_in[12], (u16*)W, flags);

    qgen_kernel<<<8192, 256, 0, stream>>>(d_in[0], wTa, q, flags);

    gemm1_fused<<<1024, 256, 0, stream>>>(
        q, d_in[0], wWc, wBc, y1, 256, flags);

    ln1_kernel<<<512, 512, 0, stream>>>(y1, wG1, wB1l, wTf, x1, fq);

    gemm2_fused<<<256, 512, 0, stream>>>(
        fq, wW1, wB1, wW2, wB2, x1, wG2, wB2l, d_out, flags);
}

// Round 10
// 301.320 us; speedup vs baseline: 1.1312x; 1.0165x over previous
//
#include <hip/hip_runtime.h>
#include <stdint.h>

typedef unsigned short u16;
typedef __bf16 bf16x8 __attribute__((ext_vector_type(8)));
typedef float f32x4 __attribute__((ext_vector_type(4)));

#define AS1(p) ((const __attribute__((address_space(1))) void*)(p))
#define AS3(p) ((__attribute__((address_space(3))) void*)(p))

__device__ __forceinline__ float b2f(u16 v){
    union { unsigned u; float f; } x; x.u = ((unsigned)v) << 16; return x.f;
}
__device__ __forceinline__ u16 f2b(float f){
    union { float f; unsigned u; } x; x.f = f;
    unsigned r = x.u + 0x7FFFu + ((x.u >> 16) & 1u);
    return (u16)(r >> 16);
}

// ---------------- dtype probe: one block per input tensor (unchanged, proven) ----------------
__global__ __launch_bounds__(256) void probe_kernel(
    const u16* p0,const u16* p1,const u16* p2,const u16* p3,const u16* p4,
    const u16* p5,const u16* p6,const u16* p7,const u16* p8,const u16* p9,
    const u16* p10,const u16* p11,const u16* p12,
    int n0,int n1,int n2,int n3,int n4,int n5,int n6,int n7,int n8,int n9,
    int n10,int n11,int n12, int* flags)
{
    const u16* p; int n;
    switch (blockIdx.x) {
        case 0: p=p0; n=n0; break;   case 1: p=p1; n=n1; break;
        case 2: p=p2; n=n2; break;   case 3: p=p3; n=n3; break;
        case 4: p=p4; n=n4; break;   case 5: p=p5; n=n5; break;
        case 6: p=p6; n=n6; break;   case 7: p=p7; n=n7; break;
        case 8: p=p8; n=n8; break;   case 9: p=p9; n=n9; break;
        case 10: p=p10; n=n10; break; case 11: p=p11; n=n11; break;
        default: p=p12; n=n12; break;
    }
    int pairs = n >> 1; if (pairs > 2048) pairs = 2048;
    int strong = 0, znz = 0, tot = 0;
    for (int k = threadIdx.x; k < pairs; k += 256) {
        u16 lo = p[2*k], hi = p[2*k+1];
        int eh = (hi >> 7) & 0xFF;
        int el = (lo >> 7) & 0xFF;
        if (eh >= 0xF0 || (eh >= 1 && eh <= 0x40)) strong = 1;
        if (el >= 0xF0 || (el >= 1 && el <= 0x40)) strong = 1;
        if (lo == 0 && hi != 0) znz++;
        tot++;
    }
    __shared__ int ss, sz, st;
    if (threadIdx.x == 0) { ss = 0; sz = 0; st = 0; }
    __syncthreads();
    if (strong) atomicOr(&ss, 1);
    if (znz) atomicAdd(&sz, znz);
    atomicAdd(&st, tot);
    __syncthreads();
    if (threadIdx.x == 0) {
        flags[blockIdx.x] = (ss || (2 * sz > st)) ? 1 : 0;
        if (blockIdx.x == 0) flags[15] = 0;
    }
}

// ---------------- convert weight/vector tensors to bf16 (Tf -> f32) in ws (unchanged) -----------
__global__ __launch_bounds__(256) void convert_kernel(
    const void* sWc, const void* sW2, const void* sW1,
    const void* sTa, const void* sBc, const void* sG1, const void* sB1l,
    const void* sTf, const void* sB1, const void* sB2, const void* sG2, const void* sB2l,
    u16* wbase, const int* flags)
{
    int b = blockIdx.x;
    const void* src; u16* dst; int n, fi, lb, tof32 = 0;
    if (b < 128)      { src=sWc; dst=wbase;          n=262144;  fi=2;  lb=b; }
    else if (b < 640) { src=sW2; dst=wbase+262144;   n=1048576; fi=9;  lb=b-128; }
    else if (b >= 643 && b < 651) { src=sW1; dst=wbase+1312256; n=16384; fi=7; lb=b-643; }
    else {
        lb = 0;
        switch (b) {
            case 640: src=sTa;  dst=wbase+1310720; n=512;  fi=1;  break;
            case 641: src=sBc;  dst=wbase+1311232; n=512;  fi=3;  break;
            case 642: src=sB2;  dst=wbase+1311744; n=512;  fi=10; break;
            case 651: src=sB1;  dst=wbase+1328640; n=2048; fi=8;  break;
            case 652: src=sG1;  dst=wbase+1330688; n=512;  fi=4;  break;
            case 653: src=sB1l; dst=wbase+1331200; n=512;  fi=5;  break;
            case 654: src=sG2;  dst=wbase+1331712; n=512;  fi=11; break;
            case 655: src=sB2l; dst=wbase+1332224; n=512;  fi=12; break;
            default:  src=sTf;  dst=wbase+1332736; n=8;    fi=6;  tof32=1; break;
        }
    }
    int i = lb * 256 + threadIdx.x;
    if (i * 8 >= n) return;
    if (tof32) {
        float* fd = (float*)dst;
        if (flags[fi]) {
            const float4* s = (const float4*)src;
            ((float4*)fd)[i*2] = s[i*2]; ((float4*)fd)[i*2+1] = s[i*2+1];
        } else {
            union { uint4 v; u16 h[8]; } sb;
            sb.v = ((const uint4*)src)[i];
            #pragma unroll
            for (int j = 0; j < 8; j++) fd[i*8+j] = b2f(sb.h[j]);
        }
        return;
    }
    if (flags[fi]) {
        const float4* s = (const float4*)src;
        float4 a = s[i*2], c = s[i*2+1];
        union { uint4 v; u16 h[8]; } o;
        o.h[0]=f2b(a.x); o.h[1]=f2b(a.y); o.h[2]=f2b(a.z); o.h[3]=f2b(a.w);
        o.h[4]=f2b(c.x); o.h[5]=f2b(c.y); o.h[6]=f2b(c.z); o.h[7]=f2b(c.w);
        ((uint4*)dst)[i] = o.v;
    } else {
        ((uint4*)dst)[i] = ((const uint4*)src)[i];
    }
}

// ---------------- qgen: q[m,k] = bf16(cos(x[m,k] + theta[k])) — pure streaming ----------------
__global__ __launch_bounds__(256) void qgen_kernel(
    const void* __restrict__ x, const u16* __restrict__ theta,
    u16* __restrict__ q, const int* flags)
{
    const int idx = blockIdx.x * 256 + threadIdx.x;   // octet index, 2,097,152 total
    const int col0 = (idx * 8) & 511;
    union { uint4 v; u16 h[8]; } tb;
    tb.v = *(const uint4*)(theta + col0);
    float xv[8];
    if (flags[0]) {
        const float4* p = (const float4*)x + idx * 2;
        float4 a = p[0], b = p[1];
        xv[0]=a.x; xv[1]=a.y; xv[2]=a.z; xv[3]=a.w;
        xv[4]=b.x; xv[5]=b.y; xv[6]=b.z; xv[7]=b.w;
    } else {
        union { uint4 v; u16 h[8]; } xb;
        xb.v = ((const uint4*)x)[idx];
        #pragma unroll
        for (int e = 0; e < 8; e++) xv[e] = b2f(xb.h[e]);
    }
    union { uint4 v; u16 h[8]; } o;
    #pragma unroll
    for (int e = 0; e < 8; e++) o.h[e] = f2b(__cosf(xv[e] + b2f(tb.h[e])));
    ((uint4*)q)[idx] = o.v;
}

// ======== gemm1 + fused LN1: x1 = LN(q@Wc^T + bc + x); fq = cos(x1[:,:8]+tf) ========
// R9-playbook applied to gemm1: BM=128 x BN=512 (FULL N) x BK=64, 8 waves as 2m x 4n,
// wave = 64m x 128n, acc[4][8]. A (=q) and B (=Wc) both staged via global_load_lds
// dbuf; 1 barrier/K-step; K=512 -> 8 steps. LDS = As 32KB + Bs 128KB = 160KB exact.
// Epilogue (twice-proven phase-decoupled pattern):
//  (1) barrier; y1 = bf16(acc + bc + x_residual) dumped into Bs [128][512]; acc dies.
//  (2) barrier; per-wave row-LN from LDS -> write x1 + fq. y1 NEVER hits HBM and the
//      ln1 kernel is deleted (saves 67MB traffic + a dispatch).
// ALIASING: q aliases x1 (ws). Safe: each block reads only its OWN 128 q-rows (done
// before the last barrier), then overwrites exactly those rows. No cross-block use.
// Numerics bit-identical to the old gemm1->ln1 path (y1 f2b-rounded before LN; fq
// from pre-rounding f32 xn).
__global__ __launch_bounds__(512, 2) void gemm1_fused(
    const u16* q, const void* __restrict__ x,
    const u16* __restrict__ Wt, const u16* __restrict__ bias,
    const u16* __restrict__ g1, const u16* __restrict__ b1l,
    const float* __restrict__ tf,
    u16* x1out, u16* __restrict__ fqout, const int* flags)
{
    __shared__ __align__(16) u16 As[2][128 * 64];
    __shared__ __align__(16) u16 Bs[2][512 * 64];
    const int K = 512, N = 512;
    const int tid  = threadIdx.x;
    const int lane = tid & 63;
    const int w    = tid >> 6;

    const int m0 = blockIdx.x * 128;

    const int srow = lane >> 3;
    const int scol = ((lane & 7) ^ srow) * 8;
    const int wm = (w >> 2) * 64;          // 2 waves per 64-row m-range
    const int wn = (w & 3) * 128;          // 4 n-positions of 128
    const int fr   = lane & 15;
    const int quad = lane >> 4;
    const int fx   = fr & 7;
    const int isf32 = flags[0];

    f32x4 acc[4][8];
    #pragma unroll
    for (int i = 0; i < 4; i++)
        #pragma unroll
        for (int jj = 0; jj < 8; jj++)
            acc[i][jj] = f32x4{0.f, 0.f, 0.f, 0.f};

    const u16* Abase = q  + (size_t)m0 * K + scol;
    const u16* Bbase = Wt + scol;

    // prologue: stage buf 0 (A: 16 chunks of 8 rows; B: 64 chunks of 8 rows)
    #pragma unroll
    for (int i = 0; i < 2; i++) {
        int c = w * 2 + i;
        int row = c * 8 + srow;
        __builtin_amdgcn_global_load_lds(AS1(Abase + (size_t)row * K),
                                         AS3(&As[0][c * 512]), 16, 0, 0);
    }
    #pragma unroll
    for (int i = 0; i < 8; i++) {
        int c = w * 8 + i;
        int row = c * 8 + srow;
        __builtin_amdgcn_global_load_lds(AS1(Bbase + (size_t)row * K),
                                         AS3(&Bs[0][c * 512]), 16, 0, 0);
    }

    int cur = 0;
    for (int kt = 0; kt < K; kt += 64) {
        __syncthreads();               // buf[cur] staged (vmcnt drained at barrier)
        if (kt + 64 < K) {             // issue next-tile staging; flies under MFMA
            int nxt = cur ^ 1;
            #pragma unroll
            for (int i = 0; i < 2; i++) {
                int c = w * 2 + i;
                int row = c * 8 + srow;
                __builtin_amdgcn_global_load_lds(
                    AS1(Abase + (size_t)row * K + kt + 64),
                    AS3(&As[nxt][c * 512]), 16, 0, 0);
            }
            #pragma unroll
            for (int i = 0; i < 8; i++) {
                int c = w * 8 + i;
                int row = c * 8 + srow;
                __builtin_amdgcn_global_load_lds(
                    AS1(Bbase + (size_t)row * K + kt + 64),
                    AS3(&Bs[nxt][c * 512]), 16, 0, 0);
            }
        }
        #pragma unroll
        for (int kk = 0; kk < 2; kk++) {
            bf16x8 af[4];
            #pragma unroll
            for (int mi = 0; mi < 4; mi++)
                af[mi] = *(const bf16x8*)(&As[cur][(wm + mi * 16 + fr) * 64 +
                                          (((kk * 4 + quad) ^ fx) * 8)]);
            #pragma unroll
            for (int np = 0; np < 4; np++) {
                bf16x8 bfr[2];
                #pragma unroll
                for (int ni = 0; ni < 2; ni++)
                    bfr[ni] = *(const bf16x8*)(&Bs[cur][(wn + (np * 2 + ni) * 16 + fr) * 64 +
                                               (((kk * 4 + quad) ^ fx) * 8)]);
                #pragma unroll
                for (int mi = 0; mi < 4; mi++)
                    #pragma unroll
                    for (int ni = 0; ni < 2; ni++)
                        acc[mi][np * 2 + ni] = __builtin_amdgcn_mfma_f32_16x16x32_bf16(
                            af[mi], bfr[ni], acc[mi][np * 2 + ni], 0, 0, 0);
            }
        }
        cur ^= 1;
    }

    // ============ phase 1: dump y1 = bf16(acc + bc + x) into LDS [128][512] ============
    __syncthreads();                    // all waves done reading As/Bs
    u16* zt = &Bs[0][0];                // 128 rows x 512 cols bf16 = 128 KB
    #pragma unroll
    for (int mi = 0; mi < 4; mi++) {
        #pragma unroll
        for (int nq = 0; nq < 8; nq++) {
            int n = wn + nq * 16 + fr;
            float bn = b2f(bias[n]);
            #pragma unroll
            for (int r = 0; r < 4; r++) {
                int lm = wm + mi * 16 + quad * 4 + r;
                float rv = isf32 ? ((const float*)x)[(size_t)(m0 + lm) * N + n]
                                 : b2f(((const u16*)x)[(size_t)(m0 + lm) * N + n]);
                zt[lm * 512 + n] = f2b(acc[mi][nq][r] + bn + rv);
            }
        }
    }
    __syncthreads();                    // y1 tile complete; acc dead

    // ============ phase 2: LN1 over complete rows in LDS; write x1 + fq ============
    {
        union { uint4 v; u16 s[8]; } gb, bb;
        gb.v = *(const uint4*)(g1 + lane * 8);
        bb.v = *(const uint4*)(b1l + lane * 8);
        for (int i = 0; i < 16; i++) {
            int row = w * 16 + i;
            union { uint4 v; u16 s[8]; } zb;
            zb.v = ((const uint4*)(zt + row * 512))[lane];
            float xv[8], s = 0.f, ss = 0.f;
            #pragma unroll
            for (int jj = 0; jj < 8; jj++) {
                xv[jj] = b2f(zb.s[jj]); s += xv[jj]; ss += xv[jj] * xv[jj];
            }
            #pragma unroll
            for (int o = 32; o > 0; o >>= 1) { s += __shfl_down(s, o); ss += __shfl_down(ss, o); }
            s = __shfl(s, 0); ss = __shfl(ss, 0);
            float mu = s * (1.f / 512.f);
            float rs = rsqrtf(ss * (1.f / 512.f) - mu * mu + 1e-5f);
            float xn[8];
            union { uint4 v; u16 s[8]; } ob;
            #pragma unroll
            for (int jj = 0; jj < 8; jj++) {
                xn[jj] = (xv[jj] - mu) * rs * b2f(gb.s[jj]) + b2f(bb.s[jj]);
                ob.s[jj] = f2b(xn[jj]);
            }
            ((uint4*)(x1out + (size_t)(m0 + row) * 512))[lane] = ob.v;
            if (lane == 0) {
                #pragma unroll
                for (int jj = 0; jj < 8; jj++)
                    fqout[(size_t)(m0 + row) * 8 + jj] = f2b(__cosf(xn[jj] + tf[jj]));
            }
        }
    }
}

// ======== gemm2 + fused LN2: out = LN(h@W2 + b2 + x1) ========
// R9 exact (proven: VGPR 124, no spill, 108.8us). Main loop R5 geometry; phase-
// decoupled LN2 epilogue (dump z to Bs, fresh LN phase, store d_out).
__global__ __launch_bounds__(512, 2) void gemm2_fused(
    const u16* __restrict__ fq, const u16* __restrict__ W1, const u16* __restrict__ b1,
    const u16* __restrict__ Wt, const u16* __restrict__ bias,
    const u16* __restrict__ res, const u16* __restrict__ g2, const u16* __restrict__ b2l,
    void* __restrict__ out, const int* flags)
{
    __shared__ __align__(16) u16 Bs[2][512 * 64];
    const int K = 2048, N = 512;
    const int tid  = threadIdx.x;
    const int lane = tid & 63;
    const int w    = tid >> 6;

    const int m0 = blockIdx.x * 128;

    const int srow = lane >> 3;
    const int scol = ((lane & 7) ^ srow) * 8;
    const int wm = (w >> 2) * 64;          // 2 waves per 64-row m-range
    const int wn = (w & 3) * 128;          // 4 n-positions of 128
    const int fr   = lane & 15;
    const int quad = lane >> 4;
    const int fx   = fr & 7;
    const int isf32 = flags[0];

    // fq B-frags for h-gen: wave's own 4 m-subtiles (m = m0+wm+mi*16+fr), quad0 holds data.
    bf16x8 fqf[4];
    #pragma unroll
    for (int mi = 0; mi < 4; mi++) {
        union { uint4 v; bf16x8 b; } z; z.v = uint4{0,0,0,0};
        if (quad == 0) z.v = *(const uint4*)(fq + (size_t)(m0 + wm + mi * 16 + fr) * 8);
        fqf[mi] = z.b;
    }

    // interleaved W1-row index for h-gen MFMA g (quad0 lanes supply A rows):
    const int krow = ((fr >> 2) * 8) + (fr & 3);      // + kt + (g>>1)*32 + (g&1)*4

    // W1 frags + b1 frags for kt=0 (proven layout)
    union { uint4 v; bf16x8 b; } w1f[4];
    uint2 b1f[4];
    #pragma unroll
    for (int g = 0; g < 4; g++) {
        w1f[g].v = uint4{0,0,0,0};
        if (quad == 0)
            w1f[g].v = *(const uint4*)(W1 + (size_t)((g >> 1) * 32 + (g & 1) * 4 + krow) * 8);
        b1f[g] = *(const uint2*)(b1 + (g >> 1) * 32 + (g & 1) * 4 + quad * 8);
    }

    f32x4 acc[4][8];
    #pragma unroll
    for (int i = 0; i < 4; i++)
        #pragma unroll
        for (int jj = 0; jj < 8; jj++)
            acc[i][jj] = f32x4{0.f, 0.f, 0.f, 0.f};

    // B staging: rows are n (0..511), full N. 8 row-groups of 8 per wave-issue set.
    const u16* Bbase = Wt + scol;
    #pragma unroll
    for (int i = 0; i < 8; i++) {
        int c = w * 8 + i;
        int row = c * 8 + srow;
        __builtin_amdgcn_global_load_lds(AS1(Bbase + (size_t)row * K),
                                         AS3(&Bs[0][c * 512]), 16, 0, 0);
    }

    int cur = 0;
    for (int kt = 0; kt < K; kt += 64) {
        __syncthreads();               // Bs[cur] staged, w1f/b1f for this kt ready
        if (kt + 64 < K) {             // issue next Bs staging; flies under compute
            int nxt = cur ^ 1;
            #pragma unroll
            for (int i = 0; i < 8; i++) {
                int c = w * 8 + i;
                int row = c * 8 + srow;
                __builtin_amdgcn_global_load_lds(
                    AS1(Bbase + (size_t)row * K + kt + 64),
                    AS3(&Bs[nxt][c * 512]), 16, 0, 0);
            }
        }
        #pragma unroll
        for (int kk = 0; kk < 2; kk++) {
            // ---- h-gen: af for all 4 mi (register-direct, proven identity) ----
            const u16* pb0 = (const u16*)&b1f[kk * 2 + 0];
            const u16* pb1 = (const u16*)&b1f[kk * 2 + 1];
            f32x4 c0 = {b2f(pb0[0]), b2f(pb0[1]), b2f(pb0[2]), b2f(pb0[3])};
            f32x4 c1 = {b2f(pb1[0]), b2f(pb1[1]), b2f(pb1[2]), b2f(pb1[3])};
            bf16x8 af[4];
            #pragma unroll
            for (int mi = 0; mi < 4; mi++) {
                f32x4 hv0 = __builtin_amdgcn_mfma_f32_16x16x32_bf16(
                    w1f[kk * 2 + 0].b, fqf[mi], c0, 0, 0, 0);
                f32x4 hv1 = __builtin_amdgcn_mfma_f32_16x16x32_bf16(
                    w1f[kk * 2 + 1].b, fqf[mi], c1, 0, 0, 0);
                #pragma unroll
                for (int r = 0; r < 4; r++) {
                    af[mi][r]     = (__bf16)fmaxf(hv0[r], 0.f);
                    af[mi][4 + r] = (__bf16)fmaxf(hv1[r], 0.f);
                }
            }
            // ---- main MFMA over the wave's 128 n, bfr in PAIRS ----
            #pragma unroll
            for (int np = 0; np < 4; np++) {
                bf16x8 bfr[2];
                #pragma unroll
                for (int ni = 0; ni < 2; ni++)
                    bfr[ni] = *(const bf16x8*)(&Bs[cur][(wn + (np * 2 + ni) * 16 + fr) * 64 +
                                               (((kk * 4 + quad) ^ fx) * 8)]);
                #pragma unroll
                for (int mi = 0; mi < 4; mi++)
                    #pragma unroll
                    for (int ni = 0; ni < 2; ni++)
                        acc[mi][np * 2 + ni] = __builtin_amdgcn_mfma_f32_16x16x32_bf16(
                            af[mi], bfr[ni], acc[mi][np * 2 + ni], 0, 0, 0);
            }
        }
        // prefetch next kt's W1/b1 frags (tiny, L1/L2-resident)
        if (kt + 64 < K) {
            #pragma unroll
            for (int g = 0; g < 4; g++) {
                if (quad == 0)
                    w1f[g].v = *(const uint4*)(W1 +
                        (size_t)(kt + 64 + (g >> 1) * 32 + (g & 1) * 4 + krow) * 8);
                b1f[g] = *(const uint2*)(b1 + kt + 64 + (g >> 1) * 32 + (g & 1) * 4 + quad * 8);
            }
        }
        cur ^= 1;
    }

    // ============ phase 1: dump z = bf16(acc + b2 + res) into LDS [128][512] ============
    __syncthreads();                    // all waves done reading Bs
    u16* zt = &Bs[0][0];                // 128 rows x 512 cols bf16 = 128 KB
    #pragma unroll
    for (int mi = 0; mi < 4; mi++) {
        #pragma unroll
        for (int nq = 0; nq < 8; nq++) {
            int n = wn + nq * 16 + fr;
            float bn = b2f(bias[n]);
            #pragma unroll
            for (int r = 0; r < 4; r++) {
                int lm = wm + mi * 16 + quad * 4 + r;
                float v = acc[mi][nq][r] + bn + b2f(res[(size_t)(m0 + lm) * N + n]);
                zt[lm * 512 + n] = f2b(v);
            }
        }
    }
    __syncthreads();                    // z tile complete; acc dead

    // ============ phase 2: LN over complete rows in LDS (ln2 verbatim) ============
    {
        union { uint4 v; u16 s[8]; } gb, bb;
        gb.v = *(const uint4*)(g2 + lane * 8);
        bb.v = *(const uint4*)(b2l + lane * 8);
        for (int i = 0; i < 16; i++) {
            int row = w * 16 + i;
            union { uint4 v; u16 s[8]; } zb;
            zb.v = ((const uint4*)(zt + row * 512))[lane];
            float xv[8], s = 0.f, ss = 0.f;
            #pragma unroll
            for (int jj = 0; jj < 8; jj++) {
                xv[jj] = b2f(zb.s[jj]); s += xv[jj]; ss += xv[jj] * xv[jj];
            }
            #pragma unroll
            for (int o = 32; o > 0; o >>= 1) { s += __shfl_down(s, o); ss += __shfl_down(ss, o); }
            s = __shfl(s, 0); ss = __shfl(ss, 0);
            float mu = s * (1.f / 512.f);
            float rs = rsqrtf(ss * (1.f / 512.f) - mu * mu + 1e-5f);
            size_t m = (size_t)(m0 + row);
            if (isf32) {
                float xn[8];
                #pragma unroll
                for (int jj = 0; jj < 8; jj++)
                    xn[jj] = (xv[jj] - mu) * rs * b2f(gb.s[jj]) + b2f(bb.s[jj]);
                float* po = (float*)out + m * N + lane * 8;
                *(float4*)po       = float4{xn[0], xn[1], xn[2], xn[3]};
                *(float4*)(po + 4) = float4{xn[4], xn[5], xn[6], xn[7]};
            } else {
                union { uint4 v; u16 s[8]; } ob;
                #pragma unroll
                for (int jj = 0; jj < 8; jj++)
                    ob.s[jj] = f2b((xv[jj] - mu) * rs * b2f(gb.s[jj]) + b2f(bb.s[jj]));
                ((uint4*)((u16*)out + m * N))[lane] = ob.v;
            }
        }
    }
}

extern "C" void kernel_launch(void* const* d_in, const int* in_sizes, int n_in,
                              void* d_out, int out_size, void* d_ws, size_t ws_size,
                              hipStream_t stream)
{
    u16* ws16 = (u16*)d_ws;
    // ws (u16 elems): W [0,1332752) | flags @1332752 | fq @1332800 (262144)
    //                 x1 @1594944 (16.7M)
    // q (cos(x+theta), bf16) ALIASES the x1 region: q live [qgen, gemm1 K-loop);
    // gemm1's epilogue overwrites its own q rows with x1. y1 and z are never
    // materialized (LN1 fused into gemm1, LN2 fused into gemm2).
    u16* W     = ws16;
    int* flags = (int*)(ws16 + 1332752);
    u16* fq  = ws16 + 1332800;
    u16* x1  = ws16 + 1594944;
    u16* q   = x1;

    const u16*  wWc  = W;
    const u16*  wW2  = W + 262144;
    const u16*  wTa  = W + 1310720;
    const u16*  wBc  = W + 1311232;
    const u16*  wB2  = W + 1311744;
    const u16*  wW1  = W + 1312256;
    const u16*  wB1  = W + 1328640;
    const u16*  wG1  = W + 1330688;
    const u16*  wB1l = W + 1331200;
    const u16*  wG2  = W + 1331712;
    const u16*  wB2l = W + 1332224;
    const float* wTf = (const float*)(W + 1332736);

    probe_kernel<<<13, 256, 0, stream>>>(
        (const u16*)d_in[0], (const u16*)d_in[1], (const u16*)d_in[2],
        (const u16*)d_in[3], (const u16*)d_in[4], (const u16*)d_in[5],
        (const u16*)d_in[6], (const u16*)d_in[7], (const u16*)d_in[8],
        (const u16*)d_in[9], (const u16*)d_in[10], (const u16*)d_in[11],
        (const u16*)d_in[12],
        in_sizes[0], in_sizes[1], in_sizes[2], in_sizes[3], in_sizes[4],
        in_sizes[5], in_sizes[6], in_sizes[7], in_sizes[8], in_sizes[9],
        in_sizes[10], in_sizes[11], in_sizes[12], flags);

    convert_kernel<<<657, 256, 0, stream>>>(
        d_in[2], d_in[9], d_in[7], d_in[1], d_in[3], d_in[4], d_in[5],
        d_in[6], d_in[8], d_in[10], d_in[11], d_in[12], (u16*)W, flags);

    qgen_kernel<<<8192, 256, 0, stream>>>(d_in[0], wTa, q, flags);

    gemm1_fused<<<256, 512, 0, stream>>>(
        q, d_in[0], wWc, wBc, wG1, wB1l, wTf, x1, fq, flags);

    gemm2_fused<<<256, 512, 0, stream>>>(
        fq, wW1, wB1, wW2, wB2, x1, wG2, wB2l, d_out, flags);
}